// Round 4
// baseline (16471.255 us; speedup 1.0000x reference)
//
#include <hip/hip_runtime.h>
#include <cstdint>

#define NE_N   100000
#define NPER_N 50000
#define HD     128
#define OUTD   64
#define NEE    1600000
#define NPE    800000
#define NEP    800000

static inline int ceil_div(long long a, long long b){ return (int)((a + b - 1)/b); }

__device__ __forceinline__ float4 ld4(const float* p){ return *reinterpret_cast<const float4*>(p); }
__device__ __forceinline__ void st4(float* p, float4 v){ *reinterpret_cast<float4*>(p) = v; }

// ================= GEMM v3 =================
// C_seg[N x 64] = (relu?)(A[N x K] @ W_seg[K x 64] + bias_seg)
// One 64-col weight segment per blockIdx.y (uniform select). W staged once in LDS
// (K*64*4B <= 32KB). A streamed global->reg with one-chunk prefetch; 16 lanes share
// each A row address (broadcast coalesce). Thread tile 4 rows x 4 cols -> low VGPR.
template<int K, bool RELU>
__global__ __launch_bounds__(256, 4)
void gemm3(const float* __restrict__ A, int N, int ldw, int ldc,
           const float* __restrict__ W0, const float* __restrict__ W1,
           const float* __restrict__ W2, const float* __restrict__ W3,
           const float* __restrict__ b0, const float* __restrict__ b1,
           const float* __restrict__ b2, const float* __restrict__ b3,
           float* __restrict__ C0, float* __restrict__ C1,
           float* __restrict__ C2, float* __restrict__ C3)
{
    __shared__ float Ws[K][64];

    const float* W; const float* bb; float* C;
    if      (blockIdx.y == 0){ W=W0; bb=b0; C=C0; }
    else if (blockIdx.y == 1){ W=W1; bb=b1; C=C1; }
    else if (blockIdx.y == 2){ W=W2; bb=b2; C=C2; }
    else                     { W=W3; bb=b3; C=C3; }

    const int t = threadIdx.x;
    // stage W segment: K rows x 64 cols
    for (int i = t; i < K*16; i += 256){
        int r = i >> 4, c = (i & 15) * 4;
        st4(&Ws[r][c], ld4(&W[(size_t)r*ldw + c]));
    }
    __syncthreads();

    const int tx = t & 15, ty = t >> 4;
    const int c0 = tx * 4;
    const int r0 = blockIdx.x*64 + ty*4;

    const float* Ar[4];
#pragma unroll
    for (int i=0;i<4;i++){ int r = r0+i; if (r > N-1) r = N-1; Ar[i] = A + (size_t)r*K; }

    float4 acc[4];
#pragma unroll
    for (int i=0;i<4;i++) acc[i] = make_float4(0.f,0.f,0.f,0.f);

    float4 acur[4];
#pragma unroll
    for (int i=0;i<4;i++) acur[i] = ld4(Ar[i]);

#pragma unroll
    for (int k0=0; k0<K; k0+=4){
        float4 anxt[4];
        if (k0+4 < K){
#pragma unroll
            for (int i=0;i<4;i++) anxt[i] = ld4(Ar[i] + k0 + 4);
        }
#pragma unroll
        for (int kk=0;kk<4;kk++){
            float4 w = ld4(&Ws[k0+kk][c0]);
#pragma unroll
            for (int i=0;i<4;i++){
                float av = (kk==0)?acur[i].x:(kk==1)?acur[i].y:(kk==2)?acur[i].z:acur[i].w;
                acc[i].x = fmaf(av, w.x, acc[i].x);
                acc[i].y = fmaf(av, w.y, acc[i].y);
                acc[i].z = fmaf(av, w.z, acc[i].z);
                acc[i].w = fmaf(av, w.w, acc[i].w);
            }
        }
        if (k0+4 < K){
#pragma unroll
            for (int i=0;i<4;i++) acur[i] = anxt[i];
        }
    }

    float4 bias = make_float4(0.f,0.f,0.f,0.f);
    if (bb) bias = ld4(bb + c0);
#pragma unroll
    for (int i=0;i<4;i++){
        int r = r0 + i;
        if (r < N){
            float4 o;
            o.x = acc[i].x + bias.x;
            o.y = acc[i].y + bias.y;
            o.z = acc[i].z + bias.z;
            o.w = acc[i].w + bias.w;
            if (RELU){
                o.x=fmaxf(o.x,0.f); o.y=fmaxf(o.y,0.f);
                o.z=fmaxf(o.z,0.f); o.w=fmaxf(o.w,0.f);
            }
            st4(&C[(size_t)r*ldc + c0], o);
        }
    }
}

// ================= CSR build =================
__global__ void count_int(const int* __restrict__ dst, int* __restrict__ cnt, int E){
    int i = blockIdx.x*blockDim.x + threadIdx.x;
    if (i < E) atomicAdd(&cnt[dst[i]], 1);
}
__global__ __launch_bounds__(256)
void scan_block(const int* __restrict__ cnt, int* __restrict__ off,
                int* __restrict__ partial, int n){
    __shared__ int sh[256];
    int t = threadIdx.x;
    int base = blockIdx.x*1024 + t*4;
    int v0 = (base  <n)?cnt[base  ]:0;
    int v1 = (base+1<n)?cnt[base+1]:0;
    int v2 = (base+2<n)?cnt[base+2]:0;
    int v3 = (base+3<n)?cnt[base+3]:0;
    int tsum = v0+v1+v2+v3;
    sh[t]=tsum; __syncthreads();
    for (int d=1; d<256; d<<=1){
        int x = (t>=d)? sh[t-d] : 0;
        __syncthreads();
        sh[t] += x;
        __syncthreads();
    }
    int ex = sh[t]-tsum;
    if (base  <n) off[base  ]=ex;
    if (base+1<n) off[base+1]=ex+v0;
    if (base+2<n) off[base+2]=ex+v0+v1;
    if (base+3<n) off[base+3]=ex+v0+v1+v2;
    if (t==255) partial[blockIdx.x]=sh[255];
}
__global__ void scan_partial(int* __restrict__ partial, int nb){
    if (threadIdx.x==0 && blockIdx.x==0){
        int run=0;
        for (int i=0;i<nb;i++){ int v=partial[i]; partial[i]=run; run+=v; }
    }
}
__global__ void add_base(int* __restrict__ off, const int* __restrict__ partial, int n, int total){
    int i = blockIdx.x*blockDim.x + threadIdx.x;
    if (i < n) off[i] += partial[i>>10];
    else if (i == n) off[n] = total;
}
__global__ void fill_csr(const int* __restrict__ src, const int* __restrict__ dst,
                         const int* __restrict__ off, int* __restrict__ cnt,
                         int* __restrict__ csr, int E){
    int i = blockIdx.x*blockDim.x + threadIdx.x;
    if (i >= E) return;
    int d = dst[i];
    int old = atomicAdd(&cnt[d], -1);
    csr[off[d] + old - 1] = src[i];
}

// ================= gather-side aggregation (shfl-broadcast indices) =================
__global__ __launch_bounds__(256)
void agg_emp1(const float* __restrict__ proj_ee, const float* __restrict__ proj_pe,
              const int* __restrict__ ee_off, const int* __restrict__ ee_csr,
              const int* __restrict__ pe_off, const int* __restrict__ pe_csr,
              float* __restrict__ emp1){
    int w    = (blockIdx.x*blockDim.x + threadIdx.x) >> 6;
    int lane = threadIdx.x & 63;
    if (w >= NE_N) return;
    float ax=0.f, ay=0.f;
    int b = ee_off[w], e = ee_off[w+1];
    int dee = e-b;
    for (int cb=b; cb<e; cb+=64){
        int j = cb+lane;
        int myidx = (j<e)? ee_csr[j] : 0;
        int lim = min(64, e-cb);
        for (int q=0;q<lim;q++){
            int s = __shfl(myidx, q, 64);
            float2 v = *reinterpret_cast<const float2*>(&proj_ee[(size_t)s*128 + lane*2]);
            ax += v.x; ay += v.y;
        }
    }
    float s1 = 1.f/fmaxf((float)dee,1.f);
    float bx=0.f, by=0.f;
    b = pe_off[w]; e = pe_off[w+1];
    int dpe = e-b;
    for (int cb=b; cb<e; cb+=64){
        int j = cb+lane;
        int myidx = (j<e)? pe_csr[j] : 0;
        int lim = min(64, e-cb);
        for (int q=0;q<lim;q++){
            int s = __shfl(myidx, q, 64);
            float2 v = *reinterpret_cast<const float2*>(&proj_pe[(size_t)s*128 + lane*2]);
            bx += v.x; by += v.y;
        }
    }
    float s2 = 1.f/fmaxf((float)dpe,1.f);
    float* row = &emp1[(size_t)w*128 + lane*2];
    float2 self = *reinterpret_cast<float2*>(row);
    float2 o;
    o.x = fmaxf(self.x + ax*s1 + bx*s2, 0.f);
    o.y = fmaxf(self.y + ay*s1 + by*s2, 0.f);
    *reinterpret_cast<float2*>(row) = o;
}
__global__ __launch_bounds__(256)
void agg_per1(const float* __restrict__ proj_ep,
              const int* __restrict__ ep_off, const int* __restrict__ ep_csr,
              float* __restrict__ per1){
    int w    = (blockIdx.x*blockDim.x + threadIdx.x) >> 6;
    int lane = threadIdx.x & 63;
    if (w >= NPER_N) return;
    float ax=0.f, ay=0.f;
    int b = ep_off[w], e = ep_off[w+1];
    int deg = e-b;
    for (int cb=b; cb<e; cb+=64){
        int j = cb+lane;
        int myidx = (j<e)? ep_csr[j] : 0;
        int lim = min(64, e-cb);
        for (int q=0;q<lim;q++){
            int s = __shfl(myidx, q, 64);
            float2 v = *reinterpret_cast<const float2*>(&proj_ep[(size_t)s*128 + lane*2]);
            ax += v.x; ay += v.y;
        }
    }
    float s1 = 1.f/fmaxf((float)deg,1.f);
    float* row = &per1[(size_t)w*128 + lane*2];
    float2 self = *reinterpret_cast<float2*>(row);
    float2 o;
    o.x = fmaxf(self.x + ax*s1, 0.f);
    o.y = fmaxf(self.y + ay*s1, 0.f);
    *reinterpret_cast<float2*>(row) = o;
}
__global__ __launch_bounds__(256)
void agg_per2(const float* __restrict__ p2ep,
              const int* __restrict__ ep_off, const int* __restrict__ ep_csr,
              float* __restrict__ out){
    int w    = (blockIdx.x*blockDim.x + threadIdx.x) >> 6;
    int lane = threadIdx.x & 63;
    if (w >= NPER_N) return;
    float a=0.f;
    int b = ep_off[w], e = ep_off[w+1];
    int deg = e-b;
    for (int cb=b; cb<e; cb+=64){
        int j = cb+lane;
        int myidx = (j<e)? ep_csr[j] : 0;
        int lim = min(64, e-cb);
        for (int q=0;q<lim;q++){
            int s = __shfl(myidx, q, 64);
            a += p2ep[(size_t)s*64 + lane];
        }
    }
    float s1 = 1.f/fmaxf((float)deg,1.f);
    out[(size_t)w*64 + lane] += a*s1;
}
__global__ __launch_bounds__(256)
void gat_sage_emp2(const int* __restrict__ ee_off, const int* __restrict__ ee_csr,
                   const int* __restrict__ pe_off, const int* __restrict__ pe_csr,
                   const float* __restrict__ as, const float* __restrict__ ad,
                   const float* __restrict__ zs, const float* __restrict__ p2pe,
                   float* __restrict__ out){
    int w    = (blockIdx.x*blockDim.x + threadIdx.x) >> 6;
    int lane = threadIdx.x & 63;
    if (w >= NE_N) return;

    float acc = 0.f;
    int b = ee_off[w], e = ee_off[w+1];
    if (e > b){
        float add = ad[w];
        float m = -INFINITY;
        for (int j=b+lane; j<e; j+=64){
            float ev = as[ee_csr[j]] + add;
            ev = ev > 0.f ? ev : 0.2f*ev;
            m = fmaxf(m, ev);
        }
        for (int o=32;o;o>>=1) m = fmaxf(m, __shfl_xor(m,o,64));
        float den = 0.f;
        for (int j=b+lane; j<e; j+=64){
            float ev = as[ee_csr[j]] + add;
            ev = ev > 0.f ? ev : 0.2f*ev;
            den += expf(ev - m);
        }
        for (int o=32;o;o>>=1) den += __shfl_xor(den,o,64);
        float invden = 1.f/den;
        for (int cb=b; cb<e; cb+=64){
            int j = cb+lane;
            int s = 0; float al = 0.f;
            if (j < e){
                s = ee_csr[j];
                float ev = as[s] + add;
                ev = ev > 0.f ? ev : 0.2f*ev;
                al = expf(ev - m)*invden;
            }
            int lim = min(64, e-cb);
            for (int q=0;q<lim;q++){
                int   sq = __shfl(s, q, 64);
                float aq = __shfl(al, q, 64);
                acc += zs[(size_t)sq*64 + lane]*aq;
            }
        }
    }
    float a2 = 0.f;
    b = pe_off[w]; e = pe_off[w+1];
    int deg = e-b;
    for (int cb=b; cb<e; cb+=64){
        int j = cb+lane;
        int s = (j<e)? pe_csr[j] : 0;
        int lim = min(64, e-cb);
        for (int q=0;q<lim;q++){
            int sq = __shfl(s,q,64);
            a2 += p2pe[(size_t)sq*64 + lane];
        }
    }
    float s2 = 1.f/fmaxf((float)deg,1.f);
    out[(size_t)w*64 + lane] += acc + a2*s2;
}

// GEMV helpers
__global__ void rowdot64(const float* __restrict__ X, const float* __restrict__ w,
                         float* __restrict__ out, int N){
    int wid  = (blockIdx.x*blockDim.x + threadIdx.x) >> 6;
    int lane = threadIdx.x & 63;
    if (wid >= N) return;
    float v = X[(size_t)wid*64 + lane]*w[lane];
    for (int o=32;o;o>>=1) v += __shfl_xor(v,o,64);
    if (lane==0) out[wid]=v;
}
__global__ void rowdot128(const float* __restrict__ X, const float* __restrict__ w,
                          float* __restrict__ out, int N){
    int wid  = (blockIdx.x*blockDim.x + threadIdx.x) >> 6;
    int lane = threadIdx.x & 63;
    if (wid >= N) return;
    float v = X[(size_t)wid*128 + lane]*w[lane] + X[(size_t)wid*128 + 64 + lane]*w[64+lane];
    for (int o=32;o;o>>=1) v += __shfl_xor(v,o,64);
    if (lane==0) out[wid]=v;
}

__global__ void prep_kernel(const float* __restrict__ Wr_ee, const float* __restrict__ Wr_pe,
                            const float* __restrict__ bl_ee, const float* __restrict__ bl_pe,
                            const float* __restrict__ s2_pe_bl, const float* __restrict__ gat_b,
                            const float* __restrict__ Wdst, const float* __restrict__ adst,
                            float* __restrict__ Wsum, float* __restrict__ bsum1,
                            float* __restrict__ b2sum, float* __restrict__ v){
    int t = threadIdx.x;
    for (int i=t;i<HD*HD;i+=256) Wsum[i]=Wr_ee[i]+Wr_pe[i];
    if (t<HD) bsum1[t]=bl_ee[t]+bl_pe[t];
    if (t<OUTD) b2sum[t]=s2_pe_bl[t]+gat_b[t];
    if (t<HD){
        float s=0.f;
        for (int c=0;c<OUTD;c++) s += Wdst[t*OUTD+c]*adst[c];
        v[t]=s;
    }
}

// ---------------- workspace layout (4-byte units) ----------------
constexpr size_t OFF_A     = 0;          // h_emp 12.8M ; later: as @ +0, ad @ +100000
constexpr size_t OFF_B     = 12800000;   // h_per 6.4M
constexpr size_t OFF_C     = 19200000;   // emp1 12.8M
constexpr size_t OFF_D     = 32000000;   // per1 6.4M
constexpr size_t OFF_E     = 38400000;   // proj_ee ; later proj_ep ; later p2pe+p2ep
constexpr size_t OFF_F     = 51200000;   // proj_pe ; later zs
constexpr size_t OFF_WSUM  = 57600000;
constexpr size_t OFF_BSUM1 = 57616384;
constexpr size_t OFF_B2SUM = 57616512;
constexpr size_t OFF_V     = 57616576;
constexpr size_t OFF_EE_CNT = 57700000;
constexpr size_t OFF_EE_OFF = 57800000;
constexpr size_t OFF_PE_CNT = 57900008;
constexpr size_t OFF_PE_OFF = 58000008;
constexpr size_t OFF_EP_CNT = 58100016;
constexpr size_t OFF_EP_OFF = 58150016;
constexpr size_t OFF_PART   = 58200024;
constexpr size_t OFF_EE_CSR = 58200280;
constexpr size_t OFF_PE_CSR = 59800280;
constexpr size_t OFF_EP_CSR = 60600280;

extern "C" void kernel_launch(void* const* d_in, const int* in_sizes, int n_in,
                              void* d_out, int out_size, void* d_ws, size_t ws_size,
                              hipStream_t stream)
{
    const float* x_emp = (const float*)d_in[0];
    const float* x_per = (const float*)d_in[1];
    const int* ee_src = (const int*)d_in[2];
    const int* ee_dst = (const int*)d_in[3];
    const int* pe_src = (const int*)d_in[4];
    const int* pe_dst = (const int*)d_in[5];
    const int* ep_src = (const int*)d_in[6];
    const int* ep_dst = (const int*)d_in[7];
    const float* lin_emp_w=(const float*)d_in[8],  *lin_emp_b=(const float*)d_in[9];
    const float* lin_per_w=(const float*)d_in[10], *lin_per_b=(const float*)d_in[11];
    const float* s1_ee_Wl=(const float*)d_in[12], *s1_ee_bl=(const float*)d_in[13], *s1_ee_Wr=(const float*)d_in[14];
    const float* s1_pe_Wl=(const float*)d_in[15], *s1_pe_bl=(const float*)d_in[16], *s1_pe_Wr=(const float*)d_in[17];
    const float* s1_ep_Wl=(const float*)d_in[18], *s1_ep_bl=(const float*)d_in[19], *s1_ep_Wr=(const float*)d_in[20];
    const float* gat_Wsrc=(const float*)d_in[21], *gat_Wdst=(const float*)d_in[22];
    const float* gat_asrc=(const float*)d_in[23], *gat_adst=(const float*)d_in[24], *gat_b=(const float*)d_in[25];
    const float* s2_pe_Wl=(const float*)d_in[26], *s2_pe_bl=(const float*)d_in[27], *s2_pe_Wr=(const float*)d_in[28];
    const float* s2_ep_Wl=(const float*)d_in[29], *s2_ep_bl=(const float*)d_in[30], *s2_ep_Wr=(const float*)d_in[31];

    float* ws = (float*)d_ws;
    int*   wi = (int*)d_ws;
    float* out_emp = (float*)d_out;
    float* out_per = out_emp + (size_t)NE_N*OUTD;

    float* h_emp = ws + OFF_A;
    float* h_per = ws + OFF_B;
    float* emp1  = ws + OFF_C;
    float* per1  = ws + OFF_D;
    float* proj_ee = ws + OFF_E;     // also proj_ep (after agg_emp1)
    float* proj_pe = ws + OFF_F;
    float* p2pe  = ws + OFF_E;
    float* p2ep  = ws + OFF_E + 3200000;
    float* zs    = ws + OFF_F;
    float* a_s   = ws + OFF_A;
    float* a_d   = ws + OFF_A + 100000;
    float* Wsum  = ws + OFF_WSUM;
    float* bsum1 = ws + OFF_BSUM1;
    float* b2sum = ws + OFF_B2SUM;
    float* vvec  = ws + OFF_V;

    int* ee_cnt = wi + OFF_EE_CNT; int* ee_off = wi + OFF_EE_OFF; int* ee_csr = wi + OFF_EE_CSR;
    int* pe_cnt = wi + OFF_PE_CNT; int* pe_off = wi + OFF_PE_OFF; int* pe_csr = wi + OFF_PE_CSR;
    int* ep_cnt = wi + OFF_EP_CNT; int* ep_off = wi + OFF_EP_OFF; int* ep_csr = wi + OFF_EP_CSR;
    int* part   = wi + OFF_PART;

    const int GE64 = ceil_div(NE_N,64), GP64 = ceil_div(NPER_N,64);

    // ---- CSR build ----
    hipMemsetAsync(ee_cnt, 0, 100000*sizeof(int), stream);
    hipMemsetAsync(pe_cnt, 0, 100000*sizeof(int), stream);
    hipMemsetAsync(ep_cnt, 0,  50000*sizeof(int), stream);

    prep_kernel<<<1,256,0,stream>>>(s1_ee_Wr, s1_pe_Wr, s1_ee_bl, s1_pe_bl,
                                    s2_pe_bl, gat_b, gat_Wdst, gat_adst,
                                    Wsum, bsum1, b2sum, vvec);

    count_int<<<ceil_div(NEE,256),256,0,stream>>>(ee_dst, ee_cnt, NEE);
    count_int<<<ceil_div(NPE,256),256,0,stream>>>(pe_dst, pe_cnt, NPE);
    count_int<<<ceil_div(NEP,256),256,0,stream>>>(ep_dst, ep_cnt, NEP);

    {   int nb = ceil_div(NE_N,1024);
        scan_block<<<nb,256,0,stream>>>(ee_cnt, ee_off, part, NE_N);
        scan_partial<<<1,64,0,stream>>>(part, nb);
        add_base<<<ceil_div(NE_N+1,256),256,0,stream>>>(ee_off, part, NE_N, NEE);
        fill_csr<<<ceil_div(NEE,256),256,0,stream>>>(ee_src, ee_dst, ee_off, ee_cnt, ee_csr, NEE);
    }
    {   int nb = ceil_div(NE_N,1024);
        scan_block<<<nb,256,0,stream>>>(pe_cnt, pe_off, part, NE_N);
        scan_partial<<<1,64,0,stream>>>(part, nb);
        add_base<<<ceil_div(NE_N+1,256),256,0,stream>>>(pe_off, part, NE_N, NPE);
        fill_csr<<<ceil_div(NPE,256),256,0,stream>>>(pe_src, pe_dst, pe_off, pe_cnt, pe_csr, NPE);
    }
    {   int nb = ceil_div(NPER_N,1024);
        scan_block<<<nb,256,0,stream>>>(ep_cnt, ep_off, part, NPER_N);
        scan_partial<<<1,64,0,stream>>>(part, nb);
        add_base<<<ceil_div(NPER_N+1,256),256,0,stream>>>(ep_off, part, NPER_N, NEP);
        fill_csr<<<ceil_div(NEP,256),256,0,stream>>>(ep_src, ep_dst, ep_off, ep_cnt, ep_csr, NEP);
    }

    // ---- input projections ----
    // G1: x_emp @ lin_emp_w (128 cols -> 2 segs), relu
    gemm3<64,true><<<dim3(GE64,2),256,0,stream>>>(x_emp, NE_N, 128, 128,
        lin_emp_w, lin_emp_w+64, nullptr, nullptr,
        lin_emp_b, lin_emp_b+64, nullptr, nullptr,
        h_emp, h_emp+64, nullptr, nullptr);
    // G2: x_per @ lin_per_w, relu
    gemm3<32,true><<<dim3(GP64,2),256,0,stream>>>(x_per, NPER_N, 128, 128,
        lin_per_w, lin_per_w+64, nullptr, nullptr,
        lin_per_b, lin_per_b+64, nullptr, nullptr,
        h_per, h_per+64, nullptr, nullptr);

    // ---- conv1 ----
    // G3a: h_emp @ [Wsum(+bsum1) -> emp1 | s1_ee_Wl -> proj_ee]   (4 segs)
    gemm3<128,false><<<dim3(GE64,4),256,0,stream>>>(h_emp, NE_N, 128, 128,
        Wsum, Wsum+64, s1_ee_Wl, s1_ee_Wl+64,
        bsum1, bsum1+64, nullptr, nullptr,
        emp1, emp1+64, proj_ee, proj_ee+64);
    // G4: h_per @ [s1_pe_Wl -> proj_pe | s1_ep_Wr(+bl) -> per1]   (4 segs)
    gemm3<128,false><<<dim3(GP64,4),256,0,stream>>>(h_per, NPER_N, 128, 128,
        s1_pe_Wl, s1_pe_Wl+64, s1_ep_Wr, s1_ep_Wr+64,
        nullptr, nullptr, s1_ep_bl, s1_ep_bl+64,
        proj_pe, proj_pe+64, per1, per1+64);
    agg_emp1<<<ceil_div((long long)NE_N*64,256),256,0,stream>>>(proj_ee, proj_pe, ee_off, ee_csr, pe_off, pe_csr, emp1);

    // G3b: h_emp @ s1_ep_Wl -> proj_ep (reuses proj_ee slot), 2 segs
    gemm3<128,false><<<dim3(GE64,2),256,0,stream>>>(h_emp, NE_N, 128, 128,
        s1_ep_Wl, s1_ep_Wl+64, nullptr, nullptr,
        nullptr, nullptr, nullptr, nullptr,
        proj_ee, proj_ee+64, nullptr, nullptr);
    agg_per1<<<ceil_div((long long)NPER_N*64,256),256,0,stream>>>(proj_ee, ep_off, ep_csr, per1);

    // ---- conv2 ----
    // G5: emp1 @ [gat_Wsrc -> zs | s2_ep_Wl -> p2ep | s2_pe_Wr(+b2sum) -> out_emp]
    gemm3<128,false><<<dim3(GE64,3),256,0,stream>>>(emp1, NE_N, 64, 64,
        gat_Wsrc, s2_ep_Wl, s2_pe_Wr, nullptr,
        nullptr, nullptr, b2sum, nullptr,
        zs, p2ep, out_emp, nullptr);
    rowdot64 <<<ceil_div(NE_N,4),256,0,stream>>>(zs,   gat_asrc, a_s, NE_N);
    rowdot128<<<ceil_div(NE_N,4),256,0,stream>>>(emp1, vvec,     a_d, NE_N);
    // G6: per1 @ [s2_pe_Wl -> p2pe | s2_ep_Wr(+bl) -> out_per]
    gemm3<128,false><<<dim3(GP64,2),256,0,stream>>>(per1, NPER_N, 64, 64,
        s2_pe_Wl, s2_ep_Wr, nullptr, nullptr,
        nullptr, s2_ep_bl, nullptr, nullptr,
        p2pe, out_per, nullptr, nullptr);

    gat_sage_emp2<<<ceil_div((long long)NE_N*64,256),256,0,stream>>>(ee_off, ee_csr, pe_off, pe_csr, a_s, a_d, zs, p2pe, out_emp);
    agg_per2<<<ceil_div((long long)NPER_N*64,256),256,0,stream>>>(p2ep, ep_off, ep_csr, out_per);
}

// Round 5
// 1413.227 us; speedup vs baseline: 11.6551x; 11.6551x over previous
//
#include <hip/hip_runtime.h>
#include <cstdint>

#define NE_N   100000
#define NPER_N 50000
#define HD     128
#define OUTD   64
#define NEE    1600000
#define NPE    800000
#define NEP    800000

static inline int ceil_div(long long a, long long b){ return (int)((a + b - 1)/b); }

__device__ __forceinline__ float4 ld4(const float* p){ return *reinterpret_cast<const float4*>(p); }
__device__ __forceinline__ void st4(float* p, float4 v){ *reinterpret_cast<float4*>(p) = v; }
__device__ __forceinline__ float4 f4fma(float s, float4 a, float4 b){
    b.x += s*a.x; b.y += s*a.y; b.z += s*a.z; b.w += s*a.w; return b; }
__device__ __forceinline__ float4 f4add(float4 a, float4 b){
    a.x+=b.x; a.y+=b.y; a.z+=b.z; a.w+=b.w; return a; }
__device__ __forceinline__ float4 f4relu(float4 a){
    a.x=fmaxf(a.x,0.f); a.y=fmaxf(a.y,0.f); a.z=fmaxf(a.z,0.f); a.w=fmaxf(a.w,0.f); return a; }

// ================= GEMM (round-1 proven codegen, M=64 config + ldw/ldc) =================
// C[N x 64-slice] = (relu?)(A[N x K] @ W[K x 64-slice] + bias). block dim3(8,32):
// thread = 4 rows x 8 cols; W slice staged in LDS (K*64*4B <= 32KB); A read from
// global in-loop (8 lanes broadcast-share each row address). No launch-bounds min,
// no prefetch registers — the exact structure that benched OK in rounds 1-2.
template<int K, bool RELU, bool BIAS>
__global__ __launch_bounds__(256)
void gemm64(const float* __restrict__ A, int N, int ldw, int ldc,
            const float* __restrict__ W, const float* __restrict__ bias,
            float* __restrict__ C)
{
    __shared__ float Ws[K*64];
    const int tid = threadIdx.y*blockDim.x + threadIdx.x;
    for (int i = tid; i < K*16; i += 256){
        int r = i >> 4, c = (i & 15) * 4;
        st4(&Ws[r*64 + c], ld4(&W[(size_t)r*ldw + c]));
    }
    __syncthreads();

    const int tx = threadIdx.x, ty = threadIdx.y;
    const int c0 = tx*8;
    const int r0 = blockIdx.x*128 + ty*4;

    const float* Ar[4];
#pragma unroll
    for (int i=0;i<4;i++){ int r=r0+i; if (r>N-1) r=N-1; Ar[i]=A+(size_t)r*K; }

    float4 acc0[4], acc1[4];
#pragma unroll
    for (int i=0;i<4;i++){ acc0[i]=make_float4(0,0,0,0); acc1[i]=make_float4(0,0,0,0); }

    for (int k=0;k<K;k+=4){
        float4 a[4];
#pragma unroll
        for (int i=0;i<4;i++) a[i]=ld4(Ar[i]+k);
#pragma unroll
        for (int kk=0;kk<4;kk++){
            float4 w0 = ld4(&Ws[(k+kk)*64 + c0]);
            float4 w1 = ld4(&Ws[(k+kk)*64 + c0 + 4]);
#pragma unroll
            for (int i=0;i<4;i++){
                float av = (kk==0)?a[i].x:(kk==1)?a[i].y:(kk==2)?a[i].z:a[i].w;
                acc0[i]=f4fma(av,w0,acc0[i]);
                acc1[i]=f4fma(av,w1,acc1[i]);
            }
        }
    }

    float4 b0=make_float4(0,0,0,0), b1=b0;
    if (BIAS){ b0=ld4(bias+c0); b1=ld4(bias+c0+4); }
#pragma unroll
    for (int i=0;i<4;i++){
        int r=r0+i;
        if (r<N){
            float4 o0=acc0[i], o1=acc1[i];
            if (BIAS){ o0=f4add(o0,b0); o1=f4add(o1,b1); }
            if (RELU){ o0=f4relu(o0); o1=f4relu(o1); }
            st4(&C[(size_t)r*ldc+c0],   o0);
            st4(&C[(size_t)r*ldc+c0+4], o1);
        }
    }
}

// ================= CSR build =================
__global__ void count_int(const int* __restrict__ dst, int* __restrict__ cnt, int E){
    int i = blockIdx.x*blockDim.x + threadIdx.x;
    if (i < E) atomicAdd(&cnt[dst[i]], 1);
}
__global__ __launch_bounds__(256)
void scan_block(const int* __restrict__ cnt, int* __restrict__ off,
                int* __restrict__ partial, int n){
    __shared__ int sh[256];
    int t = threadIdx.x;
    int base = blockIdx.x*1024 + t*4;
    int v0 = (base  <n)?cnt[base  ]:0;
    int v1 = (base+1<n)?cnt[base+1]:0;
    int v2 = (base+2<n)?cnt[base+2]:0;
    int v3 = (base+3<n)?cnt[base+3]:0;
    int tsum = v0+v1+v2+v3;
    sh[t]=tsum; __syncthreads();
    for (int d=1; d<256; d<<=1){
        int x = (t>=d)? sh[t-d] : 0;
        __syncthreads();
        sh[t] += x;
        __syncthreads();
    }
    int ex = sh[t]-tsum;
    if (base  <n) off[base  ]=ex;
    if (base+1<n) off[base+1]=ex+v0;
    if (base+2<n) off[base+2]=ex+v0+v1;
    if (base+3<n) off[base+3]=ex+v0+v1+v2;
    if (t==255) partial[blockIdx.x]=sh[255];
}
__global__ void scan_partial(int* __restrict__ partial, int nb){
    if (threadIdx.x==0 && blockIdx.x==0){
        int run=0;
        for (int i=0;i<nb;i++){ int v=partial[i]; partial[i]=run; run+=v; }
    }
}
__global__ void add_base(int* __restrict__ off, const int* __restrict__ partial, int n, int total){
    int i = blockIdx.x*blockDim.x + threadIdx.x;
    if (i < n) off[i] += partial[i>>10];
    else if (i == n) off[n] = total;
}
__global__ void fill_csr(const int* __restrict__ src, const int* __restrict__ dst,
                         const int* __restrict__ off, int* __restrict__ cnt,
                         int* __restrict__ csr, int E){
    int i = blockIdx.x*blockDim.x + threadIdx.x;
    if (i >= E) return;
    int d = dst[i];
    int old = atomicAdd(&cnt[d], -1);
    csr[off[d] + old - 1] = src[i];
}

// ================= gather-side aggregation (shfl-broadcast indices) =================
__global__ __launch_bounds__(256)
void agg_emp1(const float* __restrict__ proj_ee, const float* __restrict__ proj_pe,
              const int* __restrict__ ee_off, const int* __restrict__ ee_csr,
              const int* __restrict__ pe_off, const int* __restrict__ pe_csr,
              float* __restrict__ emp1){
    int w    = (blockIdx.x*blockDim.x + threadIdx.x) >> 6;
    int lane = threadIdx.x & 63;
    if (w >= NE_N) return;
    float ax=0.f, ay=0.f;
    int b = ee_off[w], e = ee_off[w+1];
    int dee = e-b;
    for (int cb=b; cb<e; cb+=64){
        int j = cb+lane;
        int myidx = (j<e)? ee_csr[j] : 0;
        int lim = min(64, e-cb);
        for (int q=0;q<lim;q++){
            int s = __shfl(myidx, q, 64);
            float2 v = *reinterpret_cast<const float2*>(&proj_ee[(size_t)s*128 + lane*2]);
            ax += v.x; ay += v.y;
        }
    }
    float s1 = 1.f/fmaxf((float)dee,1.f);
    float bx=0.f, by=0.f;
    b = pe_off[w]; e = pe_off[w+1];
    int dpe = e-b;
    for (int cb=b; cb<e; cb+=64){
        int j = cb+lane;
        int myidx = (j<e)? pe_csr[j] : 0;
        int lim = min(64, e-cb);
        for (int q=0;q<lim;q++){
            int s = __shfl(myidx, q, 64);
            float2 v = *reinterpret_cast<const float2*>(&proj_pe[(size_t)s*128 + lane*2]);
            bx += v.x; by += v.y;
        }
    }
    float s2 = 1.f/fmaxf((float)dpe,1.f);
    float* row = &emp1[(size_t)w*128 + lane*2];
    float2 self = *reinterpret_cast<float2*>(row);
    float2 o;
    o.x = fmaxf(self.x + ax*s1 + bx*s2, 0.f);
    o.y = fmaxf(self.y + ay*s1 + by*s2, 0.f);
    *reinterpret_cast<float2*>(row) = o;
}
__global__ __launch_bounds__(256)
void agg_per1(const float* __restrict__ proj_ep,
              const int* __restrict__ ep_off, const int* __restrict__ ep_csr,
              float* __restrict__ per1){
    int w    = (blockIdx.x*blockDim.x + threadIdx.x) >> 6;
    int lane = threadIdx.x & 63;
    if (w >= NPER_N) return;
    float ax=0.f, ay=0.f;
    int b = ep_off[w], e = ep_off[w+1];
    int deg = e-b;
    for (int cb=b; cb<e; cb+=64){
        int j = cb+lane;
        int myidx = (j<e)? ep_csr[j] : 0;
        int lim = min(64, e-cb);
        for (int q=0;q<lim;q++){
            int s = __shfl(myidx, q, 64);
            float2 v = *reinterpret_cast<const float2*>(&proj_ep[(size_t)s*128 + lane*2]);
            ax += v.x; ay += v.y;
        }
    }
    float s1 = 1.f/fmaxf((float)deg,1.f);
    float* row = &per1[(size_t)w*128 + lane*2];
    float2 self = *reinterpret_cast<float2*>(row);
    float2 o;
    o.x = fmaxf(self.x + ax*s1, 0.f);
    o.y = fmaxf(self.y + ay*s1, 0.f);
    *reinterpret_cast<float2*>(row) = o;
}
__global__ __launch_bounds__(256)
void agg_per2(const float* __restrict__ p2ep,
              const int* __restrict__ ep_off, const int* __restrict__ ep_csr,
              float* __restrict__ out){
    int w    = (blockIdx.x*blockDim.x + threadIdx.x) >> 6;
    int lane = threadIdx.x & 63;
    if (w >= NPER_N) return;
    float a=0.f;
    int b = ep_off[w], e = ep_off[w+1];
    int deg = e-b;
    for (int cb=b; cb<e; cb+=64){
        int j = cb+lane;
        int myidx = (j<e)? ep_csr[j] : 0;
        int lim = min(64, e-cb);
        for (int q=0;q<lim;q++){
            int s = __shfl(myidx, q, 64);
            a += p2ep[(size_t)s*64 + lane];
        }
    }
    float s1 = 1.f/fmaxf((float)deg,1.f);
    out[(size_t)w*64 + lane] += a*s1;
}
__global__ __launch_bounds__(256)
void gat_sage_emp2(const int* __restrict__ ee_off, const int* __restrict__ ee_csr,
                   const int* __restrict__ pe_off, const int* __restrict__ pe_csr,
                   const float* __restrict__ as, const float* __restrict__ ad,
                   const float* __restrict__ zs, const float* __restrict__ p2pe,
                   float* __restrict__ out){
    int w    = (blockIdx.x*blockDim.x + threadIdx.x) >> 6;
    int lane = threadIdx.x & 63;
    if (w >= NE_N) return;

    float acc = 0.f;
    int b = ee_off[w], e = ee_off[w+1];
    if (e > b){
        float add = ad[w];
        float m = -INFINITY;
        for (int j=b+lane; j<e; j+=64){
            float ev = as[ee_csr[j]] + add;
            ev = ev > 0.f ? ev : 0.2f*ev;
            m = fmaxf(m, ev);
        }
        for (int o=32;o;o>>=1) m = fmaxf(m, __shfl_xor(m,o,64));
        float den = 0.f;
        for (int j=b+lane; j<e; j+=64){
            float ev = as[ee_csr[j]] + add;
            ev = ev > 0.f ? ev : 0.2f*ev;
            den += expf(ev - m);
        }
        for (int o=32;o;o>>=1) den += __shfl_xor(den,o,64);
        float invden = 1.f/den;
        for (int cb=b; cb<e; cb+=64){
            int j = cb+lane;
            int s = 0; float al = 0.f;
            if (j < e){
                s = ee_csr[j];
                float ev = as[s] + add;
                ev = ev > 0.f ? ev : 0.2f*ev;
                al = expf(ev - m)*invden;
            }
            int lim = min(64, e-cb);
            for (int q=0;q<lim;q++){
                int   sq = __shfl(s, q, 64);
                float aq = __shfl(al, q, 64);
                acc += zs[(size_t)sq*64 + lane]*aq;
            }
        }
    }
    float a2 = 0.f;
    b = pe_off[w]; e = pe_off[w+1];
    int deg = e-b;
    for (int cb=b; cb<e; cb+=64){
        int j = cb+lane;
        int s = (j<e)? pe_csr[j] : 0;
        int lim = min(64, e-cb);
        for (int q=0;q<lim;q++){
            int sq = __shfl(s,q,64);
            a2 += p2pe[(size_t)sq*64 + lane];
        }
    }
    float s2 = 1.f/fmaxf((float)deg,1.f);
    out[(size_t)w*64 + lane] += acc + a2*s2;
}

// GEMV helpers
__global__ void rowdot64(const float* __restrict__ X, const float* __restrict__ w,
                         float* __restrict__ out, int N){
    int wid  = (blockIdx.x*blockDim.x + threadIdx.x) >> 6;
    int lane = threadIdx.x & 63;
    if (wid >= N) return;
    float v = X[(size_t)wid*64 + lane]*w[lane];
    for (int o=32;o;o>>=1) v += __shfl_xor(v,o,64);
    if (lane==0) out[wid]=v;
}
__global__ void rowdot128(const float* __restrict__ X, const float* __restrict__ w,
                          float* __restrict__ out, int N){
    int wid  = (blockIdx.x*blockDim.x + threadIdx.x) >> 6;
    int lane = threadIdx.x & 63;
    if (wid >= N) return;
    float v = X[(size_t)wid*128 + lane]*w[lane] + X[(size_t)wid*128 + 64 + lane]*w[64+lane];
    for (int o=32;o;o>>=1) v += __shfl_xor(v,o,64);
    if (lane==0) out[wid]=v;
}

__global__ void prep_kernel(const float* __restrict__ Wr_ee, const float* __restrict__ Wr_pe,
                            const float* __restrict__ bl_ee, const float* __restrict__ bl_pe,
                            const float* __restrict__ s2_pe_bl, const float* __restrict__ gat_b,
                            const float* __restrict__ Wdst, const float* __restrict__ adst,
                            float* __restrict__ Wsum, float* __restrict__ bsum1,
                            float* __restrict__ b2sum, float* __restrict__ v){
    int t = threadIdx.x;
    for (int i=t;i<HD*HD;i+=256) Wsum[i]=Wr_ee[i]+Wr_pe[i];
    if (t<HD) bsum1[t]=bl_ee[t]+bl_pe[t];
    if (t<OUTD) b2sum[t]=s2_pe_bl[t]+gat_b[t];
    if (t<HD){
        float s=0.f;
        for (int c=0;c<OUTD;c++) s += Wdst[t*OUTD+c]*adst[c];
        v[t]=s;
    }
}

// ---------------- workspace layout (4-byte units) ----------------
constexpr size_t OFF_A     = 0;          // h_emp 12.8M ; later: as @ +0, ad @ +100000
constexpr size_t OFF_B     = 12800000;   // h_per 6.4M
constexpr size_t OFF_C     = 19200000;   // emp1 12.8M
constexpr size_t OFF_D     = 32000000;   // per1 6.4M
constexpr size_t OFF_E     = 38400000;   // proj_ee ; later proj_ep ; later p2pe+p2ep
constexpr size_t OFF_F     = 51200000;   // proj_pe ; later zs
constexpr size_t OFF_WSUM  = 57600000;
constexpr size_t OFF_BSUM1 = 57616384;
constexpr size_t OFF_B2SUM = 57616512;
constexpr size_t OFF_V     = 57616576;
constexpr size_t OFF_EE_CNT = 57700000;
constexpr size_t OFF_EE_OFF = 57800000;
constexpr size_t OFF_PE_CNT = 57900008;
constexpr size_t OFF_PE_OFF = 58000008;
constexpr size_t OFF_EP_CNT = 58100016;
constexpr size_t OFF_EP_OFF = 58150016;
constexpr size_t OFF_PART   = 58200024;
constexpr size_t OFF_EE_CSR = 58200280;
constexpr size_t OFF_PE_CSR = 59800280;
constexpr size_t OFF_EP_CSR = 60600280;

extern "C" void kernel_launch(void* const* d_in, const int* in_sizes, int n_in,
                              void* d_out, int out_size, void* d_ws, size_t ws_size,
                              hipStream_t stream)
{
    const float* x_emp = (const float*)d_in[0];
    const float* x_per = (const float*)d_in[1];
    const int* ee_src = (const int*)d_in[2];
    const int* ee_dst = (const int*)d_in[3];
    const int* pe_src = (const int*)d_in[4];
    const int* pe_dst = (const int*)d_in[5];
    const int* ep_src = (const int*)d_in[6];
    const int* ep_dst = (const int*)d_in[7];
    const float* lin_emp_w=(const float*)d_in[8],  *lin_emp_b=(const float*)d_in[9];
    const float* lin_per_w=(const float*)d_in[10], *lin_per_b=(const float*)d_in[11];
    const float* s1_ee_Wl=(const float*)d_in[12], *s1_ee_bl=(const float*)d_in[13], *s1_ee_Wr=(const float*)d_in[14];
    const float* s1_pe_Wl=(const float*)d_in[15], *s1_pe_bl=(const float*)d_in[16], *s1_pe_Wr=(const float*)d_in[17];
    const float* s1_ep_Wl=(const float*)d_in[18], *s1_ep_bl=(const float*)d_in[19], *s1_ep_Wr=(const float*)d_in[20];
    const float* gat_Wsrc=(const float*)d_in[21], *gat_Wdst=(const float*)d_in[22];
    const float* gat_asrc=(const float*)d_in[23], *gat_adst=(const float*)d_in[24], *gat_b=(const float*)d_in[25];
    const float* s2_pe_Wl=(const float*)d_in[26], *s2_pe_bl=(const float*)d_in[27], *s2_pe_Wr=(const float*)d_in[28];
    const float* s2_ep_Wl=(const float*)d_in[29], *s2_ep_bl=(const float*)d_in[30], *s2_ep_Wr=(const float*)d_in[31];

    float* ws = (float*)d_ws;
    int*   wi = (int*)d_ws;
    float* out_emp = (float*)d_out;
    float* out_per = out_emp + (size_t)NE_N*OUTD;

    float* h_emp = ws + OFF_A;
    float* h_per = ws + OFF_B;
    float* emp1  = ws + OFF_C;
    float* per1  = ws + OFF_D;
    float* proj_ee = ws + OFF_E;     // also proj_ep (after agg_emp1)
    float* proj_pe = ws + OFF_F;
    float* p2pe  = ws + OFF_E;
    float* p2ep  = ws + OFF_E + 3200000;
    float* zs    = ws + OFF_F;
    float* a_s   = ws + OFF_A;
    float* a_d   = ws + OFF_A + 100000;
    float* Wsum  = ws + OFF_WSUM;
    float* bsum1 = ws + OFF_BSUM1;
    float* b2sum = ws + OFF_B2SUM;
    float* vvec  = ws + OFF_V;

    int* ee_cnt = wi + OFF_EE_CNT; int* ee_off = wi + OFF_EE_OFF; int* ee_csr = wi + OFF_EE_CSR;
    int* pe_cnt = wi + OFF_PE_CNT; int* pe_off = wi + OFF_PE_OFF; int* pe_csr = wi + OFF_PE_CSR;
    int* ep_cnt = wi + OFF_EP_CNT; int* ep_off = wi + OFF_EP_OFF; int* ep_csr = wi + OFF_EP_CSR;
    int* part   = wi + OFF_PART;

    const int GE = ceil_div(NE_N,128), GP = ceil_div(NPER_N,128);

    // ---- CSR build ----
    hipMemsetAsync(ee_cnt, 0, 100000*sizeof(int), stream);
    hipMemsetAsync(pe_cnt, 0, 100000*sizeof(int), stream);
    hipMemsetAsync(ep_cnt, 0,  50000*sizeof(int), stream);

    prep_kernel<<<1,256,0,stream>>>(s1_ee_Wr, s1_pe_Wr, s1_ee_bl, s1_pe_bl,
                                    s2_pe_bl, gat_b, gat_Wdst, gat_adst,
                                    Wsum, bsum1, b2sum, vvec);

    count_int<<<ceil_div(NEE,256),256,0,stream>>>(ee_dst, ee_cnt, NEE);
    count_int<<<ceil_div(NPE,256),256,0,stream>>>(pe_dst, pe_cnt, NPE);
    count_int<<<ceil_div(NEP,256),256,0,stream>>>(ep_dst, ep_cnt, NEP);

    {   int nb = ceil_div(NE_N,1024);
        scan_block<<<nb,256,0,stream>>>(ee_cnt, ee_off, part, NE_N);
        scan_partial<<<1,64,0,stream>>>(part, nb);
        add_base<<<ceil_div(NE_N+1,256),256,0,stream>>>(ee_off, part, NE_N, NEE);
        fill_csr<<<ceil_div(NEE,256),256,0,stream>>>(ee_src, ee_dst, ee_off, ee_cnt, ee_csr, NEE);
    }
    {   int nb = ceil_div(NE_N,1024);
        scan_block<<<nb,256,0,stream>>>(pe_cnt, pe_off, part, NE_N);
        scan_partial<<<1,64,0,stream>>>(part, nb);
        add_base<<<ceil_div(NE_N+1,256),256,0,stream>>>(pe_off, part, NE_N, NPE);
        fill_csr<<<ceil_div(NPE,256),256,0,stream>>>(pe_src, pe_dst, pe_off, pe_cnt, pe_csr, NPE);
    }
    {   int nb = ceil_div(NPER_N,1024);
        scan_block<<<nb,256,0,stream>>>(ep_cnt, ep_off, part, NPER_N);
        scan_partial<<<1,64,0,stream>>>(part, nb);
        add_base<<<ceil_div(NPER_N+1,256),256,0,stream>>>(ep_off, part, NPER_N, NEP);
        fill_csr<<<ceil_div(NEP,256),256,0,stream>>>(ep_src, ep_dst, ep_off, ep_cnt, ep_csr, NEP);
    }

    const dim3 BLK(8,32);

    // ---- input projections (two 64-col slices each) ----
    gemm64<64,true,true><<<GE,BLK,0,stream>>>(x_emp, NE_N, 128, 128, lin_emp_w,    lin_emp_b,    h_emp);
    gemm64<64,true,true><<<GE,BLK,0,stream>>>(x_emp, NE_N, 128, 128, lin_emp_w+64, lin_emp_b+64, h_emp+64);
    gemm64<32,true,true><<<GP,BLK,0,stream>>>(x_per, NPER_N, 128, 128, lin_per_w,    lin_per_b,    h_per);
    gemm64<32,true,true><<<GP,BLK,0,stream>>>(x_per, NPER_N, 128, 128, lin_per_w+64, lin_per_b+64, h_per+64);

    // ---- conv1 ----
    gemm64<128,false,true ><<<GE,BLK,0,stream>>>(h_emp, NE_N, 128, 128, Wsum,        bsum1,    emp1);
    gemm64<128,false,true ><<<GE,BLK,0,stream>>>(h_emp, NE_N, 128, 128, Wsum+64,     bsum1+64, emp1+64);
    gemm64<128,false,false><<<GE,BLK,0,stream>>>(h_emp, NE_N, 128, 128, s1_ee_Wl,    nullptr,  proj_ee);
    gemm64<128,false,false><<<GE,BLK,0,stream>>>(h_emp, NE_N, 128, 128, s1_ee_Wl+64, nullptr,  proj_ee+64);
    gemm64<128,false,false><<<GP,BLK,0,stream>>>(h_per, NPER_N, 128, 128, s1_pe_Wl,    nullptr,   proj_pe);
    gemm64<128,false,false><<<GP,BLK,0,stream>>>(h_per, NPER_N, 128, 128, s1_pe_Wl+64, nullptr,   proj_pe+64);
    gemm64<128,false,true ><<<GP,BLK,0,stream>>>(h_per, NPER_N, 128, 128, s1_ep_Wr,    s1_ep_bl,    per1);
    gemm64<128,false,true ><<<GP,BLK,0,stream>>>(h_per, NPER_N, 128, 128, s1_ep_Wr+64, s1_ep_bl+64, per1+64);
    agg_emp1<<<ceil_div((long long)NE_N*64,256),256,0,stream>>>(proj_ee, proj_pe, ee_off, ee_csr, pe_off, pe_csr, emp1);

    gemm64<128,false,false><<<GE,BLK,0,stream>>>(h_emp, NE_N, 128, 128, s1_ep_Wl,    nullptr, proj_ee);
    gemm64<128,false,false><<<GE,BLK,0,stream>>>(h_emp, NE_N, 128, 128, s1_ep_Wl+64, nullptr, proj_ee+64);
    agg_per1<<<ceil_div((long long)NPER_N*64,256),256,0,stream>>>(proj_ee, ep_off, ep_csr, per1);

    // ---- conv2 ----
    gemm64<128,false,false><<<GE,BLK,0,stream>>>(emp1, NE_N, 64, 64, gat_Wsrc, nullptr, zs);
    gemm64<128,false,false><<<GE,BLK,0,stream>>>(emp1, NE_N, 64, 64, s2_ep_Wl, nullptr, p2ep);
    gemm64<128,false,true ><<<GE,BLK,0,stream>>>(emp1, NE_N, 64, 64, s2_pe_Wr, b2sum,   out_emp);
    rowdot64 <<<ceil_div(NE_N,4),256,0,stream>>>(zs,   gat_asrc, a_s, NE_N);
    rowdot128<<<ceil_div(NE_N,4),256,0,stream>>>(emp1, vvec,     a_d, NE_N);
    gemm64<128,false,false><<<GP,BLK,0,stream>>>(per1, NPER_N, 64, 64, s2_pe_Wl, nullptr,  p2pe);
    gemm64<128,false,true ><<<GP,BLK,0,stream>>>(per1, NPER_N, 64, 64, s2_ep_Wr, s2_ep_bl, out_per);

    gat_sage_emp2<<<ceil_div((long long)NE_N*64,256),256,0,stream>>>(ee_off, ee_csr, pe_off, pe_csr, a_s, a_d, zs, p2pe, out_emp);
    agg_per2<<<ceil_div((long long)NPER_N*64,256),256,0,stream>>>(p2ep, ep_off, ep_csr, out_per);
}

// Round 6
// 1038.458 us; speedup vs baseline: 15.8613x; 1.3609x over previous
//
#include <hip/hip_runtime.h>
#include <cstdint>

#define NE_N   100000
#define NPER_N 50000
#define HD     128
#define OUTD   64
#define NEE    1600000
#define NPE    800000
#define NEP    800000

static inline int ceil_div(long long a, long long b){ return (int)((a + b - 1)/b); }

__device__ __forceinline__ float4 ld4(const float* p){ return *reinterpret_cast<const float4*>(p); }
__device__ __forceinline__ uint16_t f2b(float f){            // fp32 -> bf16 RNE
    uint32_t u = __float_as_uint(f);
    u += 0x7fffu + ((u >> 16) & 1u);
    return (uint16_t)(u >> 16);
}
__device__ __forceinline__ float b2f(uint32_t u){ return __uint_as_float(u << 16); }

typedef short v8s __attribute__((ext_vector_type(8)));   // 8 bf16 (4 VGPRs)
typedef float v4f __attribute__((ext_vector_type(4)));   // MFMA accumulator

// ================= MFMA bf16 GEMM =================
// C_seg[N x 64] = A[N x K](bf16) @ W_seg[K x 64](bf16), fp32 accum.
// Block 256 thr = 4 waves, BM=256 (wave owns 64 rows x 64 cols = 4x4 16x16 tiles).
// A-frags straight from global (16B/lane). W transposed into LDS [col][K+8] so
// B-frag reads are contiguous ds_read_b128 (pad => <=2-way bank alias, free).
// mode: 0 = f32 out + bias ; 1 = bf16 out ; 2 = bf16 out + bias + relu
struct Seg { const uint16_t* W; const float* b; void* C; int ldw; int ldc; int mode; };
struct Segs { Seg s[6]; };

template<int K>
__global__ __launch_bounds__(256)
void gemm_mfma(const uint16_t* __restrict__ A, int N, Segs segs)
{
    constexpr int NKS  = K / 32;
    constexpr int PADK = K + 8;            // keeps 16B alignment, breaks bank stride
    __shared__ __align__(16) uint16_t Wt[64 * PADK];

    Seg sg = segs.s[blockIdx.y];

    const int t = threadIdx.x;
    for (int i = t; i < K*64; i += 256){
        int k = i >> 6, c = i & 63;
        Wt[c*PADK + k] = sg.W[(size_t)k*sg.ldw + c];
    }
    __syncthreads();

    const int lane = t & 63, wid = t >> 6;
    const int l16 = lane & 15, lg = lane >> 4;
    const int rowbase = blockIdx.x*256 + wid*64;

    v4f acc[4][4];
#pragma unroll
    for (int i=0;i<4;i++)
#pragma unroll
        for (int j=0;j<4;j++) acc[i][j] = (v4f){0.f,0.f,0.f,0.f};

#pragma unroll
    for (int ks=0; ks<NKS; ks++){
        const int koff = ks*32 + lg*8;
        v8s a[4], b[4];
#pragma unroll
        for (int rt=0;rt<4;rt++){
            int r = rowbase + rt*16 + l16; if (r > N-1) r = N-1;
            a[rt] = *reinterpret_cast<const v8s*>(&A[(size_t)r*K + koff]);
        }
#pragma unroll
        for (int ct=0;ct<4;ct++)
            b[ct] = *reinterpret_cast<const v8s*>(&Wt[(ct*16 + l16)*PADK + koff]);
#pragma unroll
        for (int rt=0;rt<4;rt++)
#pragma unroll
            for (int ct=0;ct<4;ct++)
                acc[rt][ct] = __builtin_amdgcn_mfma_f32_16x16x32_bf16(a[rt], b[ct], acc[rt][ct], 0, 0, 0);
    }

    const int mode = sg.mode, ldc = sg.ldc;
    float bias[4];
    if (mode != 1){
#pragma unroll
        for (int ct=0;ct<4;ct++) bias[ct] = sg.b[ct*16 + l16];
    }
#pragma unroll
    for (int rt=0;rt<4;rt++){
#pragma unroll
        for (int rg=0;rg<4;rg++){
            int r = rowbase + rt*16 + lg*4 + rg;
            if (r < N){
#pragma unroll
                for (int ct=0;ct<4;ct++){
                    float v = acc[rt][ct][rg];
                    int c = ct*16 + l16;
                    if (mode == 0)
                        ((float*)sg.C)[(size_t)r*ldc + c] = v + bias[ct];
                    else if (mode == 1)
                        ((uint16_t*)sg.C)[(size_t)r*ldc + c] = f2b(v);
                    else
                        ((uint16_t*)sg.C)[(size_t)r*ldc + c] = f2b(fmaxf(v + bias[ct], 0.f));
                }
            }
        }
    }
}

// ================= CSR build =================
__global__ void count_int(const int* __restrict__ dst, int* __restrict__ cnt, int E){
    int i = blockIdx.x*blockDim.x + threadIdx.x;
    if (i < E) atomicAdd(&cnt[dst[i]], 1);
}
__global__ __launch_bounds__(256)
void scan_block(const int* __restrict__ cnt, int* __restrict__ off,
                int* __restrict__ partial, int n){
    __shared__ int sh[256];
    int t = threadIdx.x;
    int base = blockIdx.x*1024 + t*4;
    int v0 = (base  <n)?cnt[base  ]:0;
    int v1 = (base+1<n)?cnt[base+1]:0;
    int v2 = (base+2<n)?cnt[base+2]:0;
    int v3 = (base+3<n)?cnt[base+3]:0;
    int tsum = v0+v1+v2+v3;
    sh[t]=tsum; __syncthreads();
    for (int d=1; d<256; d<<=1){
        int x = (t>=d)? sh[t-d] : 0;
        __syncthreads();
        sh[t] += x;
        __syncthreads();
    }
    int ex = sh[t]-tsum;
    if (base  <n) off[base  ]=ex;
    if (base+1<n) off[base+1]=ex+v0;
    if (base+2<n) off[base+2]=ex+v0+v1;
    if (base+3<n) off[base+3]=ex+v0+v1+v2;
    if (t==255) partial[blockIdx.x]=sh[255];
}
__global__ void scan_partial(int* __restrict__ partial, int nb){
    if (threadIdx.x==0 && blockIdx.x==0){
        int run=0;
        for (int i=0;i<nb;i++){ int v=partial[i]; partial[i]=run; run+=v; }
    }
}
__global__ void add_base(int* __restrict__ off, const int* __restrict__ partial, int n, int total){
    int i = blockIdx.x*blockDim.x + threadIdx.x;
    if (i < n) off[i] += partial[i>>10];
    else if (i == n) off[n] = total;
}
__global__ void fill_csr(const int* __restrict__ src, const int* __restrict__ dst,
                         const int* __restrict__ off, int* __restrict__ cnt,
                         int* __restrict__ csr, int E){
    int i = blockIdx.x*blockDim.x + threadIdx.x;
    if (i >= E) return;
    int d = dst[i];
    int old = atomicAdd(&cnt[d], -1);
    csr[off[d] + old - 1] = src[i];
}

// ================= gather-side aggregation (bf16 payloads) =================
__global__ __launch_bounds__(256)
void agg_emp1(const uint16_t* __restrict__ proj_ee, const uint16_t* __restrict__ proj_pe,
              const int* __restrict__ ee_off, const int* __restrict__ ee_csr,
              const int* __restrict__ pe_off, const int* __restrict__ pe_csr,
              const float* __restrict__ emp1f, uint16_t* __restrict__ emp1b){
    int w    = (blockIdx.x*blockDim.x + threadIdx.x) >> 6;
    int lane = threadIdx.x & 63;
    if (w >= NE_N) return;
    float ax=0.f, ay=0.f;
    int b = ee_off[w], e = ee_off[w+1];
    int dee = e-b;
    for (int cb=b; cb<e; cb+=64){
        int j = cb+lane;
        int myidx = (j<e)? ee_csr[j] : 0;
        int lim = min(64, e-cb);
        for (int q=0;q<lim;q++){
            int s = __shfl(myidx, q, 64);
            uint32_t v = *reinterpret_cast<const uint32_t*>(&proj_ee[(size_t)s*128 + lane*2]);
            ax += b2f(v & 0xffffu); ay += b2f(v >> 16);
        }
    }
    float s1 = 1.f/fmaxf((float)dee,1.f);
    float bx=0.f, by=0.f;
    b = pe_off[w]; e = pe_off[w+1];
    int dpe = e-b;
    for (int cb=b; cb<e; cb+=64){
        int j = cb+lane;
        int myidx = (j<e)? pe_csr[j] : 0;
        int lim = min(64, e-cb);
        for (int q=0;q<lim;q++){
            int s = __shfl(myidx, q, 64);
            uint32_t v = *reinterpret_cast<const uint32_t*>(&proj_pe[(size_t)s*128 + lane*2]);
            bx += b2f(v & 0xffffu); by += b2f(v >> 16);
        }
    }
    float s2 = 1.f/fmaxf((float)dpe,1.f);
    float2 self = *reinterpret_cast<const float2*>(&emp1f[(size_t)w*128 + lane*2]);
    float ox = fmaxf(self.x + ax*s1 + bx*s2, 0.f);
    float oy = fmaxf(self.y + ay*s1 + by*s2, 0.f);
    uint32_t pk = (uint32_t)f2b(ox) | ((uint32_t)f2b(oy) << 16);
    *reinterpret_cast<uint32_t*>(&emp1b[(size_t)w*128 + lane*2]) = pk;
}
__global__ __launch_bounds__(256)
void agg_per1(const uint16_t* __restrict__ proj_ep,
              const int* __restrict__ ep_off, const int* __restrict__ ep_csr,
              const float* __restrict__ per1f, uint16_t* __restrict__ per1b){
    int w    = (blockIdx.x*blockDim.x + threadIdx.x) >> 6;
    int lane = threadIdx.x & 63;
    if (w >= NPER_N) return;
    float ax=0.f, ay=0.f;
    int b = ep_off[w], e = ep_off[w+1];
    int deg = e-b;
    for (int cb=b; cb<e; cb+=64){
        int j = cb+lane;
        int myidx = (j<e)? ep_csr[j] : 0;
        int lim = min(64, e-cb);
        for (int q=0;q<lim;q++){
            int s = __shfl(myidx, q, 64);
            uint32_t v = *reinterpret_cast<const uint32_t*>(&proj_ep[(size_t)s*128 + lane*2]);
            ax += b2f(v & 0xffffu); ay += b2f(v >> 16);
        }
    }
    float s1 = 1.f/fmaxf((float)deg,1.f);
    float2 self = *reinterpret_cast<const float2*>(&per1f[(size_t)w*128 + lane*2]);
    float ox = fmaxf(self.x + ax*s1, 0.f);
    float oy = fmaxf(self.y + ay*s1, 0.f);
    uint32_t pk = (uint32_t)f2b(ox) | ((uint32_t)f2b(oy) << 16);
    *reinterpret_cast<uint32_t*>(&per1b[(size_t)w*128 + lane*2]) = pk;
}
__global__ __launch_bounds__(256)
void agg_per2(const uint16_t* __restrict__ p2ep,
              const int* __restrict__ ep_off, const int* __restrict__ ep_csr,
              float* __restrict__ out){
    int w    = (blockIdx.x*blockDim.x + threadIdx.x) >> 6;
    int lane = threadIdx.x & 63;
    if (w >= NPER_N) return;
    float a=0.f;
    int b = ep_off[w], e = ep_off[w+1];
    int deg = e-b;
    for (int cb=b; cb<e; cb+=64){
        int j = cb+lane;
        int myidx = (j<e)? ep_csr[j] : 0;
        int lim = min(64, e-cb);
        for (int q=0;q<lim;q++){
            int s = __shfl(myidx, q, 64);
            a += b2f((uint32_t)p2ep[(size_t)s*64 + lane]);
        }
    }
    float s1 = 1.f/fmaxf((float)deg,1.f);
    out[(size_t)w*64 + lane] += a*s1;
}
__global__ __launch_bounds__(256)
void gat_sage_emp2(const int* __restrict__ ee_off, const int* __restrict__ ee_csr,
                   const int* __restrict__ pe_off, const int* __restrict__ pe_csr,
                   const float* __restrict__ as, const float* __restrict__ ad,
                   const uint16_t* __restrict__ zs, const uint16_t* __restrict__ p2pe,
                   float* __restrict__ out){
    int w    = (blockIdx.x*blockDim.x + threadIdx.x) >> 6;
    int lane = threadIdx.x & 63;
    if (w >= NE_N) return;

    float acc = 0.f;
    int b = ee_off[w], e = ee_off[w+1];
    if (e > b){
        float add = ad[w];
        float m = -INFINITY;
        for (int j=b+lane; j<e; j+=64){
            float ev = as[ee_csr[j]] + add;
            ev = ev > 0.f ? ev : 0.2f*ev;
            m = fmaxf(m, ev);
        }
        for (int o=32;o;o>>=1) m = fmaxf(m, __shfl_xor(m,o,64));
        float den = 0.f;
        for (int j=b+lane; j<e; j+=64){
            float ev = as[ee_csr[j]] + add;
            ev = ev > 0.f ? ev : 0.2f*ev;
            den += expf(ev - m);
        }
        for (int o=32;o;o>>=1) den += __shfl_xor(den,o,64);
        float invden = 1.f/den;
        for (int cb=b; cb<e; cb+=64){
            int j = cb+lane;
            int s = 0; float al = 0.f;
            if (j < e){
                s = ee_csr[j];
                float ev = as[s] + add;
                ev = ev > 0.f ? ev : 0.2f*ev;
                al = expf(ev - m)*invden;
            }
            int lim = min(64, e-cb);
            for (int q=0;q<lim;q++){
                int   sq = __shfl(s, q, 64);
                float aq = __shfl(al, q, 64);
                acc += b2f((uint32_t)zs[(size_t)sq*64 + lane])*aq;
            }
        }
    }
    float a2 = 0.f;
    b = pe_off[w]; e = pe_off[w+1];
    int deg = e-b;
    for (int cb=b; cb<e; cb+=64){
        int j = cb+lane;
        int s = (j<e)? pe_csr[j] : 0;
        int lim = min(64, e-cb);
        for (int q=0;q<lim;q++){
            int sq = __shfl(s,q,64);
            a2 += b2f((uint32_t)p2pe[(size_t)sq*64 + lane]);
        }
    }
    float s2 = 1.f/fmaxf((float)deg,1.f);
    out[(size_t)w*64 + lane] += acc + a2*s2;
}

// GEMV helpers (bf16 X)
__global__ void rowdot64b(const uint16_t* __restrict__ X, const float* __restrict__ w,
                          float* __restrict__ out, int N){
    int wid  = (blockIdx.x*blockDim.x + threadIdx.x) >> 6;
    int lane = threadIdx.x & 63;
    if (wid >= N) return;
    float v = b2f((uint32_t)X[(size_t)wid*64 + lane])*w[lane];
    for (int o=32;o;o>>=1) v += __shfl_xor(v,o,64);
    if (lane==0) out[wid]=v;
}
__global__ void rowdot128b(const uint16_t* __restrict__ X, const float* __restrict__ w,
                           float* __restrict__ out, int N){
    int wid  = (blockIdx.x*blockDim.x + threadIdx.x) >> 6;
    int lane = threadIdx.x & 63;
    if (wid >= N) return;
    float v = b2f((uint32_t)X[(size_t)wid*128 + lane])*w[lane]
            + b2f((uint32_t)X[(size_t)wid*128 + 64 + lane])*w[64+lane];
    for (int o=32;o;o>>=1) v += __shfl_xor(v,o,64);
    if (lane==0) out[wid]=v;
}

// ================= prep: weight conversion to bf16 + small fusions =================
// WB offsets (bf16 element units)
constexpr int WB_WSUM   = 0;        // 128x128
constexpr int WB_EEWL   = 16384;    // 128x128
constexpr int WB_EPWL   = 32768;
constexpr int WB_PEWL   = 49152;
constexpr int WB_EPWR1  = 65536;
constexpr int WB_LINE   = 81920;    // 64x128
constexpr int WB_LINP   = 90112;    // 32x128
constexpr int WB_GATW   = 94208;    // 128x64
constexpr int WB_S2EPWL = 102400;
constexpr int WB_S2PEWR = 110592;
constexpr int WB_S2PEWL = 118784;
constexpr int WB_S2EPWR = 126976;   // end 135168

__global__ void prep(const float* Wr_ee, const float* Wr_pe,
                     const float* ee_Wl, const float* ep_Wl, const float* pe_Wl, const float* ep_Wr,
                     const float* line_w, const float* linp_w,
                     const float* gatW, const float* s2epWl, const float* s2peWr,
                     const float* s2peWl, const float* s2epWr,
                     const float* bl_ee, const float* bl_pe,
                     const float* s2_pe_bl, const float* gat_b,
                     const float* Wdst, const float* adst,
                     uint16_t* wb, float* bsum1, float* b2sum, float* vvec)
{
    int j = blockIdx.x, t = threadIdx.x;
    if (j == 12){
        if (t < HD){
            bsum1[t] = bl_ee[t] + bl_pe[t];
            float s = 0.f;
            for (int c=0;c<OUTD;c++) s += Wdst[t*OUTD + c]*adst[c];
            vvec[t] = s;
        }
        if (t < OUTD) b2sum[t] = s2_pe_bl[t] + gat_b[t];
        return;
    }
    if (j == 0){
        for (int i=t; i<16384; i+=256) wb[WB_WSUM + i] = f2b(Wr_ee[i] + Wr_pe[i]);
        return;
    }
    const float* src; uint16_t* dst; int n;
    switch(j){
        case 1:  src=ee_Wl;  dst=wb+WB_EEWL;   n=16384; break;
        case 2:  src=ep_Wl;  dst=wb+WB_EPWL;   n=16384; break;
        case 3:  src=pe_Wl;  dst=wb+WB_PEWL;   n=16384; break;
        case 4:  src=ep_Wr;  dst=wb+WB_EPWR1;  n=16384; break;
        case 5:  src=line_w; dst=wb+WB_LINE;   n=8192;  break;
        case 6:  src=linp_w; dst=wb+WB_LINP;   n=4096;  break;
        case 7:  src=gatW;   dst=wb+WB_GATW;   n=8192;  break;
        case 8:  src=s2epWl; dst=wb+WB_S2EPWL; n=8192;  break;
        case 9:  src=s2peWr; dst=wb+WB_S2PEWR; n=8192;  break;
        case 10: src=s2peWl; dst=wb+WB_S2PEWL; n=8192;  break;
        default: src=s2epWr; dst=wb+WB_S2EPWR; n=8192;  break;
    }
    for (int i=t; i<n; i+=256) dst[i] = f2b(src[i]);
}

// input fp32 -> bf16 (4 elems/thread)
__global__ void convx(const float* __restrict__ xe, const float* __restrict__ xp,
                      uint16_t* __restrict__ be, uint16_t* __restrict__ bp){
    const int NE4 = NE_N*64/4, NP4 = NPER_N*32/4;
    int i = blockIdx.x*blockDim.x + threadIdx.x;
    if (i < NE4){
        float4 v = ld4(xe + (size_t)i*4);
        uint2 o;
        o.x = (uint32_t)f2b(v.x) | ((uint32_t)f2b(v.y) << 16);
        o.y = (uint32_t)f2b(v.z) | ((uint32_t)f2b(v.w) << 16);
        *reinterpret_cast<uint2*>(&be[(size_t)i*4]) = o;
    } else if (i < NE4 + NP4){
        int k = i - NE4;
        float4 v = ld4(xp + (size_t)k*4);
        uint2 o;
        o.x = (uint32_t)f2b(v.x) | ((uint32_t)f2b(v.y) << 16);
        o.y = (uint32_t)f2b(v.z) | ((uint32_t)f2b(v.w) << 16);
        *reinterpret_cast<uint2*>(&bp[(size_t)k*4]) = o;
    }
}

// ---------------- workspace layout (float/4B units) ----------------
constexpr size_t OFF_R0 = 0;          // xbe (bf16 6.4M u16) -> zsB
constexpr size_t OFF_R1 = 3200000;    // xbp -> p2peB
constexpr size_t OFF_R2 = 4800000;    // h_empB -> emp1B
constexpr size_t OFF_R3 = 11200000;   // h_perB -> per1B
constexpr size_t OFF_R4 = 14400000;   // emp1F (f32) -> p2epB
constexpr size_t OFF_R5 = 27200000;   // per1F (f32)
constexpr size_t OFF_R6 = 33600000;   // proj_eeB
constexpr size_t OFF_R7 = 40000000;   // proj_peB
constexpr size_t OFF_R8 = 43200000;   // proj_epB
constexpr size_t OFF_AS = 49600000;   // a_s 100k
constexpr size_t OFF_AD = 49700000;   // a_d 100k
constexpr size_t OFF_WB = 49800000;   // bf16 weights (135168 u16)
constexpr size_t OFF_BS1= 49900000;   // bsum1 128
constexpr size_t OFF_BS2= 49900128;   // b2sum 64
constexpr size_t OFF_VV = 49900192;   // vvec 128
constexpr size_t OFF_EE_CNT = 50000000;
constexpr size_t OFF_EE_OFF = 50100000;
constexpr size_t OFF_PE_CNT = 50200008;
constexpr size_t OFF_PE_OFF = 50300008;
constexpr size_t OFF_EP_CNT = 50400016;
constexpr size_t OFF_EP_OFF = 50450016;
constexpr size_t OFF_PART   = 50500024;
constexpr size_t OFF_EE_CSR = 50500288;
constexpr size_t OFF_PE_CSR = 52100288;
constexpr size_t OFF_EP_CSR = 52900288;   // end ~53.7M floats = 215 MB

extern "C" void kernel_launch(void* const* d_in, const int* in_sizes, int n_in,
                              void* d_out, int out_size, void* d_ws, size_t ws_size,
                              hipStream_t stream)
{
    const float* x_emp = (const float*)d_in[0];
    const float* x_per = (const float*)d_in[1];
    const int* ee_src = (const int*)d_in[2];
    const int* ee_dst = (const int*)d_in[3];
    const int* pe_src = (const int*)d_in[4];
    const int* pe_dst = (const int*)d_in[5];
    const int* ep_src = (const int*)d_in[6];
    const int* ep_dst = (const int*)d_in[7];
    const float* lin_emp_w=(const float*)d_in[8],  *lin_emp_b=(const float*)d_in[9];
    const float* lin_per_w=(const float*)d_in[10], *lin_per_b=(const float*)d_in[11];
    const float* s1_ee_Wl=(const float*)d_in[12], *s1_ee_bl=(const float*)d_in[13], *s1_ee_Wr=(const float*)d_in[14];
    const float* s1_pe_Wl=(const float*)d_in[15], *s1_pe_bl=(const float*)d_in[16], *s1_pe_Wr=(const float*)d_in[17];
    const float* s1_ep_Wl=(const float*)d_in[18], *s1_ep_bl=(const float*)d_in[19], *s1_ep_Wr=(const float*)d_in[20];
    const float* gat_Wsrc=(const float*)d_in[21], *gat_Wdst=(const float*)d_in[22];
    const float* gat_asrc=(const float*)d_in[23], *gat_adst=(const float*)d_in[24], *gat_b=(const float*)d_in[25];
    const float* s2_pe_Wl=(const float*)d_in[26], *s2_pe_bl=(const float*)d_in[27], *s2_pe_Wr=(const float*)d_in[28];
    const float* s2_ep_Wl=(const float*)d_in[29], *s2_ep_bl=(const float*)d_in[30], *s2_ep_Wr=(const float*)d_in[31];

    float* ws = (float*)d_ws;
    int*   wi = (int*)d_ws;
    float* out_emp = (float*)d_out;
    float* out_per = out_emp + (size_t)NE_N*OUTD;

    uint16_t* xbe     = (uint16_t*)(ws + OFF_R0);
    uint16_t* zsB     = (uint16_t*)(ws + OFF_R0);
    uint16_t* xbp     = (uint16_t*)(ws + OFF_R1);
    uint16_t* p2peB   = (uint16_t*)(ws + OFF_R1);
    uint16_t* h_empB  = (uint16_t*)(ws + OFF_R2);
    uint16_t* emp1B   = (uint16_t*)(ws + OFF_R2);
    uint16_t* h_perB  = (uint16_t*)(ws + OFF_R3);
    uint16_t* per1B   = (uint16_t*)(ws + OFF_R3);
    float*    emp1F   = ws + OFF_R4;
    uint16_t* p2epB   = (uint16_t*)(ws + OFF_R4);
    float*    per1F   = ws + OFF_R5;
    uint16_t* proj_eeB= (uint16_t*)(ws + OFF_R6);
    uint16_t* proj_peB= (uint16_t*)(ws + OFF_R7);
    uint16_t* proj_epB= (uint16_t*)(ws + OFF_R8);
    float* a_s   = ws + OFF_AS;
    float* a_d   = ws + OFF_AD;
    uint16_t* WB = (uint16_t*)(ws + OFF_WB);
    float* bsum1 = ws + OFF_BS1;
    float* b2sum = ws + OFF_BS2;
    float* vvec  = ws + OFF_VV;

    int* ee_cnt = wi + OFF_EE_CNT; int* ee_off = wi + OFF_EE_OFF; int* ee_csr = wi + OFF_EE_CSR;
    int* pe_cnt = wi + OFF_PE_CNT; int* pe_off = wi + OFF_PE_OFF; int* pe_csr = wi + OFF_PE_CSR;
    int* ep_cnt = wi + OFF_EP_CNT; int* ep_off = wi + OFF_EP_OFF; int* ep_csr = wi + OFF_EP_CSR;
    int* part   = wi + OFF_PART;

    const int GE = ceil_div(NE_N,256), GP = ceil_div(NPER_N,256);

    // ---- CSR build + prep + input conversion ----
    hipMemsetAsync(ee_cnt, 0, 100000*sizeof(int), stream);
    hipMemsetAsync(pe_cnt, 0, 100000*sizeof(int), stream);
    hipMemsetAsync(ep_cnt, 0,  50000*sizeof(int), stream);

    prep<<<13,256,0,stream>>>(s1_ee_Wr, s1_pe_Wr, s1_ee_Wl, s1_ep_Wl, s1_pe_Wl, s1_ep_Wr,
                              lin_emp_w, lin_per_w,
                              gat_Wsrc, s2_ep_Wl, s2_pe_Wr, s2_pe_Wl, s2_ep_Wr,
                              s1_ee_bl, s1_pe_bl, s2_pe_bl, gat_b, gat_Wdst, gat_adst,
                              WB, bsum1, b2sum, vvec);
    convx<<<ceil_div(NE_N*64/4 + NPER_N*32/4, 256),256,0,stream>>>(x_emp, x_per, xbe, xbp);

    count_int<<<ceil_div(NEE,256),256,0,stream>>>(ee_dst, ee_cnt, NEE);
    count_int<<<ceil_div(NPE,256),256,0,stream>>>(pe_dst, pe_cnt, NPE);
    count_int<<<ceil_div(NEP,256),256,0,stream>>>(ep_dst, ep_cnt, NEP);
    {   int nb = ceil_div(NE_N,1024);
        scan_block<<<nb,256,0,stream>>>(ee_cnt, ee_off, part, NE_N);
        scan_partial<<<1,64,0,stream>>>(part, nb);
        add_base<<<ceil_div(NE_N+1,256),256,0,stream>>>(ee_off, part, NE_N, NEE);
        fill_csr<<<ceil_div(NEE,256),256,0,stream>>>(ee_src, ee_dst, ee_off, ee_cnt, ee_csr, NEE);
    }
    {   int nb = ceil_div(NE_N,1024);
        scan_block<<<nb,256,0,stream>>>(pe_cnt, pe_off, part, NE_N);
        scan_partial<<<1,64,0,stream>>>(part, nb);
        add_base<<<ceil_div(NE_N+1,256),256,0,stream>>>(pe_off, part, NE_N, NPE);
        fill_csr<<<ceil_div(NPE,256),256,0,stream>>>(pe_src, pe_dst, pe_off, pe_cnt, pe_csr, NPE);
    }
    {   int nb = ceil_div(NPER_N,1024);
        scan_block<<<nb,256,0,stream>>>(ep_cnt, ep_off, part, NPER_N);
        scan_partial<<<1,64,0,stream>>>(part, nb);
        add_base<<<ceil_div(NPER_N+1,256),256,0,stream>>>(ep_off, part, NPER_N, NEP);
        fill_csr<<<ceil_div(NEP,256),256,0,stream>>>(ep_src, ep_dst, ep_off, ep_cnt, ep_csr, NEP);
    }

    // ---- G1/G2: input projections (bf16 MFMA, relu, bf16 out) ----
    {
        Segs g{}; 
        g.s[0] = Seg{WB+WB_LINE,    lin_emp_b,    (void*)h_empB,      128,128,2};
        g.s[1] = Seg{WB+WB_LINE+64, lin_emp_b+64, (void*)(h_empB+64), 128,128,2};
        g.s[2]=g.s[0]; g.s[3]=g.s[0]; g.s[4]=g.s[0]; g.s[5]=g.s[0];
        gemm_mfma<64><<<dim3(GE,2),256,0,stream>>>(xbe, NE_N, g);
    }
    {
        Segs g{};
        g.s[0] = Seg{WB+WB_LINP,    lin_per_b,    (void*)h_perB,      128,128,2};
        g.s[1] = Seg{WB+WB_LINP+64, lin_per_b+64, (void*)(h_perB+64), 128,128,2};
        g.s[2]=g.s[0]; g.s[3]=g.s[0]; g.s[4]=g.s[0]; g.s[5]=g.s[0];
        gemm_mfma<32><<<dim3(GP,2),256,0,stream>>>(xbp, NPER_N, g);
    }

    // ---- conv1 GEMMs ----
    {   // G3: h_emp @ {Wsum -> emp1F(f32,+bsum1) | ee_Wl -> proj_ee | ep_Wl -> proj_ep}
        Segs g{};
        g.s[0] = Seg{WB+WB_WSUM,    bsum1,    (void*)emp1F,        128,128,0};
        g.s[1] = Seg{WB+WB_WSUM+64, bsum1+64, (void*)(emp1F+64),   128,128,0};
        g.s[2] = Seg{WB+WB_EEWL,    nullptr,  (void*)proj_eeB,     128,128,1};
        g.s[3] = Seg{WB+WB_EEWL+64, nullptr,  (void*)(proj_eeB+64),128,128,1};
        g.s[4] = Seg{WB+WB_EPWL,    nullptr,  (void*)proj_epB,     128,128,1};
        g.s[5] = Seg{WB+WB_EPWL+64, nullptr,  (void*)(proj_epB+64),128,128,1};
        gemm_mfma<128><<<dim3(GE,6),256,0,stream>>>(h_empB, NE_N, g);
    }
    {   // G4: h_per @ {pe_Wl -> proj_pe | ep_Wr -> per1F(f32,+bl)}
        Segs g{};
        g.s[0] = Seg{WB+WB_PEWL,    nullptr,     (void*)proj_peB,     128,128,1};
        g.s[1] = Seg{WB+WB_PEWL+64, nullptr,     (void*)(proj_peB+64),128,128,1};
        g.s[2] = Seg{WB+WB_EPWR1,   s1_ep_bl,    (void*)per1F,        128,128,0};
        g.s[3] = Seg{WB+WB_EPWR1+64,s1_ep_bl+64, (void*)(per1F+64),   128,128,0};
        g.s[4]=g.s[0]; g.s[5]=g.s[0];
        gemm_mfma<128><<<dim3(GP,4),256,0,stream>>>(h_perB, NPER_N, g);
    }
    agg_emp1<<<ceil_div((long long)NE_N*64,256),256,0,stream>>>(proj_eeB, proj_peB, ee_off, ee_csr, pe_off, pe_csr, emp1F, emp1B);
    agg_per1<<<ceil_div((long long)NPER_N*64,256),256,0,stream>>>(proj_epB, ep_off, ep_csr, per1F, per1B);

    // ---- conv2 GEMMs ----
    {   // G5: emp1 @ {gat_Wsrc -> zs | s2_ep_Wl -> p2ep | s2_pe_Wr -> out_emp(f32,+b2sum)}
        Segs g{};
        g.s[0] = Seg{WB+WB_GATW,   nullptr, (void*)zsB,     64,64,1};
        g.s[1] = Seg{WB+WB_S2EPWL, nullptr, (void*)p2epB,   64,64,1};
        g.s[2] = Seg{WB+WB_S2PEWR, b2sum,   (void*)out_emp, 64,64,0};
        g.s[3]=g.s[0]; g.s[4]=g.s[0]; g.s[5]=g.s[0];
        gemm_mfma<128><<<dim3(GE,3),256,0,stream>>>(emp1B, NE_N, g);
    }
    rowdot64b <<<ceil_div(NE_N,4),256,0,stream>>>(zsB,   gat_asrc, a_s, NE_N);
    rowdot128b<<<ceil_div(NE_N,4),256,0,stream>>>(emp1B, vvec,     a_d, NE_N);
    {   // G6: per1 @ {s2_pe_Wl -> p2pe | s2_ep_Wr -> out_per(f32,+bl)}
        Segs g{};
        g.s[0] = Seg{WB+WB_S2PEWL, nullptr,  (void*)p2peB,   64,64,1};
        g.s[1] = Seg{WB+WB_S2EPWR, s2_ep_bl, (void*)out_per, 64,64,0};
        g.s[2]=g.s[0]; g.s[3]=g.s[0]; g.s[4]=g.s[0]; g.s[5]=g.s[0];
        gemm_mfma<128><<<dim3(GP,2),256,0,stream>>>(per1B, NPER_N, g);
    }

    gat_sage_emp2<<<ceil_div((long long)NE_N*64,256),256,0,stream>>>(ee_off, ee_csr, pe_off, pe_csr, a_s, a_d, zsB, p2peB, out_emp);
    agg_per2<<<ceil_div((long long)NPER_N*64,256),256,0,stream>>>(p2epB, ep_off, ep_csr, out_per);
}

// Round 7
// 871.996 us; speedup vs baseline: 18.8891x; 1.1909x over previous
//
#include <hip/hip_runtime.h>
#include <cstdint>

#define NE_N   100000
#define NPER_N 50000
#define HD     128
#define OUTD   64
#define NEE    1600000
#define NPE    800000
#define NEP    800000

static inline int ceil_div(long long a, long long b){ return (int)((a + b - 1)/b); }

__device__ __forceinline__ float4 ld4(const float* p){ return *reinterpret_cast<const float4*>(p); }
__device__ __forceinline__ uint16_t f2b(float f){            // fp32 -> bf16 RNE
    uint32_t u = __float_as_uint(f);
    u += 0x7fffu + ((u >> 16) & 1u);
    return (uint16_t)(u >> 16);
}
__device__ __forceinline__ float b2f(uint32_t u){ return __uint_as_float(u << 16); }

typedef short v8s __attribute__((ext_vector_type(8)));   // 8 bf16 (4 VGPRs)
typedef float v4f __attribute__((ext_vector_type(4)));   // MFMA accumulator

// ================= MFMA bf16 GEMM (unchanged from round 6) =================
struct Seg { const uint16_t* W; const float* b; void* C; int ldw; int ldc; int mode; };
struct Segs { Seg s[6]; };

template<int K>
__global__ __launch_bounds__(256)
void gemm_mfma(const uint16_t* __restrict__ A, int N, Segs segs)
{
    constexpr int NKS  = K / 32;
    constexpr int PADK = K + 8;
    __shared__ __align__(16) uint16_t Wt[64 * PADK];

    Seg sg = segs.s[blockIdx.y];

    const int t = threadIdx.x;
    for (int i = t; i < K*64; i += 256){
        int k = i >> 6, c = i & 63;
        Wt[c*PADK + k] = sg.W[(size_t)k*sg.ldw + c];
    }
    __syncthreads();

    const int lane = t & 63, wid = t >> 6;
    const int l16 = lane & 15, lg = lane >> 4;
    const int rowbase = blockIdx.x*256 + wid*64;

    v4f acc[4][4];
#pragma unroll
    for (int i=0;i<4;i++)
#pragma unroll
        for (int j=0;j<4;j++) acc[i][j] = (v4f){0.f,0.f,0.f,0.f};

#pragma unroll
    for (int ks=0; ks<NKS; ks++){
        const int koff = ks*32 + lg*8;
        v8s a[4], b[4];
#pragma unroll
        for (int rt=0;rt<4;rt++){
            int r = rowbase + rt*16 + l16; if (r > N-1) r = N-1;
            a[rt] = *reinterpret_cast<const v8s*>(&A[(size_t)r*K + koff]);
        }
#pragma unroll
        for (int ct=0;ct<4;ct++)
            b[ct] = *reinterpret_cast<const v8s*>(&Wt[(ct*16 + l16)*PADK + koff]);
#pragma unroll
        for (int rt=0;rt<4;rt++)
#pragma unroll
            for (int ct=0;ct<4;ct++)
                acc[rt][ct] = __builtin_amdgcn_mfma_f32_16x16x32_bf16(a[rt], b[ct], acc[rt][ct], 0, 0, 0);
    }

    const int mode = sg.mode, ldc = sg.ldc;
    float bias[4];
    if (mode != 1){
#pragma unroll
        for (int ct=0;ct<4;ct++) bias[ct] = sg.b[ct*16 + l16];
    }
#pragma unroll
    for (int rt=0;rt<4;rt++){
#pragma unroll
        for (int rg=0;rg<4;rg++){
            int r = rowbase + rt*16 + lg*4 + rg;
            if (r < N){
#pragma unroll
                for (int ct=0;ct<4;ct++){
                    float v = acc[rt][ct][rg];
                    int c = ct*16 + l16;
                    if (mode == 0)
                        ((float*)sg.C)[(size_t)r*ldc + c] = v + bias[ct];
                    else if (mode == 1)
                        ((uint16_t*)sg.C)[(size_t)r*ldc + c] = f2b(v);
                    else
                        ((uint16_t*)sg.C)[(size_t)r*ldc + c] = f2b(fmaxf(v + bias[ct], 0.f));
                }
            }
        }
    }
}

// ================= CSR build =================
__global__ void count_int(const int* __restrict__ dst, int* __restrict__ cnt, int E){
    int i = blockIdx.x*blockDim.x + threadIdx.x;
    if (i < E) atomicAdd(&cnt[dst[i]], 1);
}
__global__ __launch_bounds__(256)
void scan_block(const int* __restrict__ cnt, int* __restrict__ off,
                int* __restrict__ partial, int n){
    __shared__ int sh[256];
    int t = threadIdx.x;
    int base = blockIdx.x*1024 + t*4;
    int v0 = (base  <n)?cnt[base  ]:0;
    int v1 = (base+1<n)?cnt[base+1]:0;
    int v2 = (base+2<n)?cnt[base+2]:0;
    int v3 = (base+3<n)?cnt[base+3]:0;
    int tsum = v0+v1+v2+v3;
    sh[t]=tsum; __syncthreads();
    for (int d=1; d<256; d<<=1){
        int x = (t>=d)? sh[t-d] : 0;
        __syncthreads();
        sh[t] += x;
        __syncthreads();
    }
    int ex = sh[t]-tsum;
    if (base  <n) off[base  ]=ex;
    if (base+1<n) off[base+1]=ex+v0;
    if (base+2<n) off[base+2]=ex+v0+v1;
    if (base+3<n) off[base+3]=ex+v0+v1+v2;
    if (t==255) partial[blockIdx.x]=sh[255];
}
__global__ void scan_partial(int* __restrict__ partial, int nb){
    if (threadIdx.x==0 && blockIdx.x==0){
        int run=0;
        for (int i=0;i<nb;i++){ int v=partial[i]; partial[i]=run; run+=v; }
    }
}
__global__ void add_base(int* __restrict__ off, const int* __restrict__ partial, int n, int total){
    int i = blockIdx.x*blockDim.x + threadIdx.x;
    if (i < n) off[i] += partial[i>>10];
    else if (i == n) off[n] = total;
}
__global__ void fill_csr(const int* __restrict__ src, const int* __restrict__ dst,
                         const int* __restrict__ off, int* __restrict__ cnt,
                         int* __restrict__ csr, int E){
    int i = blockIdx.x*blockDim.x + threadIdx.x;
    if (i >= E) return;
    int d = dst[i];
    int old = atomicAdd(&cnt[d], -1);
    csr[off[d] + old - 1] = src[i];
}

// ================= gather-side aggregation (unroll-4 broadcast for MLP) =================
__global__ __launch_bounds__(256)
void agg_emp1(const uint16_t* __restrict__ proj_ee, const uint16_t* __restrict__ proj_pe,
              const int* __restrict__ ee_off, const int* __restrict__ ee_csr,
              const int* __restrict__ pe_off, const int* __restrict__ pe_csr,
              const float* __restrict__ emp1f, uint16_t* __restrict__ emp1b){
    int w    = (blockIdx.x*blockDim.x + threadIdx.x) >> 6;
    int lane = threadIdx.x & 63;
    if (w >= NE_N) return;
    float ax=0.f, ay=0.f;
    int b = ee_off[w], e = ee_off[w+1];
    int dee = e-b;
    for (int cb=b; cb<e; cb+=64){
        int j = cb+lane;
        int myidx = (j<e)? ee_csr[j] : 0;
        int lim = min(64, e-cb);
        int q = 0;
        for (; q+4<=lim; q+=4){
            int s0=__shfl(myidx,q,64),   s1=__shfl(myidx,q+1,64);
            int s2=__shfl(myidx,q+2,64), s3=__shfl(myidx,q+3,64);
            uint32_t v0 = *reinterpret_cast<const uint32_t*>(&proj_ee[(size_t)s0*128 + lane*2]);
            uint32_t v1 = *reinterpret_cast<const uint32_t*>(&proj_ee[(size_t)s1*128 + lane*2]);
            uint32_t v2 = *reinterpret_cast<const uint32_t*>(&proj_ee[(size_t)s2*128 + lane*2]);
            uint32_t v3 = *reinterpret_cast<const uint32_t*>(&proj_ee[(size_t)s3*128 + lane*2]);
            ax += b2f(v0&0xffffu) + b2f(v1&0xffffu) + b2f(v2&0xffffu) + b2f(v3&0xffffu);
            ay += b2f(v0>>16)     + b2f(v1>>16)     + b2f(v2>>16)     + b2f(v3>>16);
        }
        for (; q<lim; q++){
            int s = __shfl(myidx, q, 64);
            uint32_t v = *reinterpret_cast<const uint32_t*>(&proj_ee[(size_t)s*128 + lane*2]);
            ax += b2f(v & 0xffffu); ay += b2f(v >> 16);
        }
    }
    float s1f = 1.f/fmaxf((float)dee,1.f);
    float bx=0.f, by=0.f;
    b = pe_off[w]; e = pe_off[w+1];
    int dpe = e-b;
    for (int cb=b; cb<e; cb+=64){
        int j = cb+lane;
        int myidx = (j<e)? pe_csr[j] : 0;
        int lim = min(64, e-cb);
        int q = 0;
        for (; q+4<=lim; q+=4){
            int s0=__shfl(myidx,q,64),   s1=__shfl(myidx,q+1,64);
            int s2=__shfl(myidx,q+2,64), s3=__shfl(myidx,q+3,64);
            uint32_t v0 = *reinterpret_cast<const uint32_t*>(&proj_pe[(size_t)s0*128 + lane*2]);
            uint32_t v1 = *reinterpret_cast<const uint32_t*>(&proj_pe[(size_t)s1*128 + lane*2]);
            uint32_t v2 = *reinterpret_cast<const uint32_t*>(&proj_pe[(size_t)s2*128 + lane*2]);
            uint32_t v3 = *reinterpret_cast<const uint32_t*>(&proj_pe[(size_t)s3*128 + lane*2]);
            bx += b2f(v0&0xffffu) + b2f(v1&0xffffu) + b2f(v2&0xffffu) + b2f(v3&0xffffu);
            by += b2f(v0>>16)     + b2f(v1>>16)     + b2f(v2>>16)     + b2f(v3>>16);
        }
        for (; q<lim; q++){
            int s = __shfl(myidx, q, 64);
            uint32_t v = *reinterpret_cast<const uint32_t*>(&proj_pe[(size_t)s*128 + lane*2]);
            bx += b2f(v & 0xffffu); by += b2f(v >> 16);
        }
    }
    float s2f = 1.f/fmaxf((float)dpe,1.f);
    float2 self = *reinterpret_cast<const float2*>(&emp1f[(size_t)w*128 + lane*2]);
    float ox = fmaxf(self.x + ax*s1f + bx*s2f, 0.f);
    float oy = fmaxf(self.y + ay*s1f + by*s2f, 0.f);
    uint32_t pk = (uint32_t)f2b(ox) | ((uint32_t)f2b(oy) << 16);
    *reinterpret_cast<uint32_t*>(&emp1b[(size_t)w*128 + lane*2]) = pk;
}
__global__ __launch_bounds__(256)
void agg_per1(const uint16_t* __restrict__ proj_ep,
              const int* __restrict__ ep_off, const int* __restrict__ ep_csr,
              const float* __restrict__ per1f, uint16_t* __restrict__ per1b){
    int w    = (blockIdx.x*blockDim.x + threadIdx.x) >> 6;
    int lane = threadIdx.x & 63;
    if (w >= NPER_N) return;
    float ax=0.f, ay=0.f;
    int b = ep_off[w], e = ep_off[w+1];
    int deg = e-b;
    for (int cb=b; cb<e; cb+=64){
        int j = cb+lane;
        int myidx = (j<e)? ep_csr[j] : 0;
        int lim = min(64, e-cb);
        int q = 0;
        for (; q+4<=lim; q+=4){
            int s0=__shfl(myidx,q,64),   s1=__shfl(myidx,q+1,64);
            int s2=__shfl(myidx,q+2,64), s3=__shfl(myidx,q+3,64);
            uint32_t v0 = *reinterpret_cast<const uint32_t*>(&proj_ep[(size_t)s0*128 + lane*2]);
            uint32_t v1 = *reinterpret_cast<const uint32_t*>(&proj_ep[(size_t)s1*128 + lane*2]);
            uint32_t v2 = *reinterpret_cast<const uint32_t*>(&proj_ep[(size_t)s2*128 + lane*2]);
            uint32_t v3 = *reinterpret_cast<const uint32_t*>(&proj_ep[(size_t)s3*128 + lane*2]);
            ax += b2f(v0&0xffffu) + b2f(v1&0xffffu) + b2f(v2&0xffffu) + b2f(v3&0xffffu);
            ay += b2f(v0>>16)     + b2f(v1>>16)     + b2f(v2>>16)     + b2f(v3>>16);
        }
        for (; q<lim; q++){
            int s = __shfl(myidx, q, 64);
            uint32_t v = *reinterpret_cast<const uint32_t*>(&proj_ep[(size_t)s*128 + lane*2]);
            ax += b2f(v & 0xffffu); ay += b2f(v >> 16);
        }
    }
    float s1f = 1.f/fmaxf((float)deg,1.f);
    float2 self = *reinterpret_cast<const float2*>(&per1f[(size_t)w*128 + lane*2]);
    float ox = fmaxf(self.x + ax*s1f, 0.f);
    float oy = fmaxf(self.y + ay*s1f, 0.f);
    uint32_t pk = (uint32_t)f2b(ox) | ((uint32_t)f2b(oy) << 16);
    *reinterpret_cast<uint32_t*>(&per1b[(size_t)w*128 + lane*2]) = pk;
}
__global__ __launch_bounds__(256)
void agg_per2(const uint16_t* __restrict__ p2ep,
              const int* __restrict__ ep_off, const int* __restrict__ ep_csr,
              float* __restrict__ out){
    int w    = (blockIdx.x*blockDim.x + threadIdx.x) >> 6;
    int lane = threadIdx.x & 63;
    if (w >= NPER_N) return;
    float a=0.f;
    int b = ep_off[w], e = ep_off[w+1];
    int deg = e-b;
    for (int cb=b; cb<e; cb+=64){
        int j = cb+lane;
        int myidx = (j<e)? ep_csr[j] : 0;
        int lim = min(64, e-cb);
        int q = 0;
        for (; q+4<=lim; q+=4){
            int s0=__shfl(myidx,q,64),   s1=__shfl(myidx,q+1,64);
            int s2=__shfl(myidx,q+2,64), s3=__shfl(myidx,q+3,64);
            float v0 = b2f((uint32_t)p2ep[(size_t)s0*64 + lane]);
            float v1 = b2f((uint32_t)p2ep[(size_t)s1*64 + lane]);
            float v2 = b2f((uint32_t)p2ep[(size_t)s2*64 + lane]);
            float v3 = b2f((uint32_t)p2ep[(size_t)s3*64 + lane]);
            a += v0 + v1 + v2 + v3;
        }
        for (; q<lim; q++){
            int s = __shfl(myidx, q, 64);
            a += b2f((uint32_t)p2ep[(size_t)s*64 + lane]);
        }
    }
    float s1f = 1.f/fmaxf((float)deg,1.f);
    out[(size_t)w*64 + lane] += a*s1f;
}
__global__ __launch_bounds__(256)
void gat_sage_emp2(const int* __restrict__ ee_off, const int* __restrict__ ee_csr,
                   const int* __restrict__ pe_off, const int* __restrict__ pe_csr,
                   const float* __restrict__ as, const float* __restrict__ ad,
                   const uint16_t* __restrict__ zs, const uint16_t* __restrict__ p2pe,
                   float* __restrict__ out){
    int w    = (blockIdx.x*blockDim.x + threadIdx.x) >> 6;
    int lane = threadIdx.x & 63;
    if (w >= NE_N) return;

    float acc = 0.f;
    int b = ee_off[w], e = ee_off[w+1];
    if (e > b){
        float add = ad[w];
        float m = -INFINITY;
        for (int j=b+lane; j<e; j+=64){
            float ev = as[ee_csr[j]] + add;
            ev = ev > 0.f ? ev : 0.2f*ev;
            m = fmaxf(m, ev);
        }
        for (int o=32;o;o>>=1) m = fmaxf(m, __shfl_xor(m,o,64));
        float den = 0.f;
        for (int j=b+lane; j<e; j+=64){
            float ev = as[ee_csr[j]] + add;
            ev = ev > 0.f ? ev : 0.2f*ev;
            den += expf(ev - m);
        }
        for (int o=32;o;o>>=1) den += __shfl_xor(den,o,64);
        float invden = 1.f/den;
        for (int cb=b; cb<e; cb+=64){
            int j = cb+lane;
            int s = 0; float al = 0.f;
            if (j < e){
                s = ee_csr[j];
                float ev = as[s] + add;
                ev = ev > 0.f ? ev : 0.2f*ev;
                al = expf(ev - m)*invden;
            }
            int lim = min(64, e-cb);
            int q = 0;
            for (; q+4<=lim; q+=4){
                int   s0=__shfl(s,q,64),    s1=__shfl(s,q+1,64);
                int   s2=__shfl(s,q+2,64),  s3=__shfl(s,q+3,64);
                float a0=__shfl(al,q,64),   a1=__shfl(al,q+1,64);
                float a2=__shfl(al,q+2,64), a3=__shfl(al,q+3,64);
                float v0 = b2f((uint32_t)zs[(size_t)s0*64 + lane]);
                float v1 = b2f((uint32_t)zs[(size_t)s1*64 + lane]);
                float v2 = b2f((uint32_t)zs[(size_t)s2*64 + lane]);
                float v3 = b2f((uint32_t)zs[(size_t)s3*64 + lane]);
                acc += v0*a0 + v1*a1 + v2*a2 + v3*a3;
            }
            for (; q<lim; q++){
                int   sq = __shfl(s, q, 64);
                float aq = __shfl(al, q, 64);
                acc += b2f((uint32_t)zs[(size_t)sq*64 + lane])*aq;
            }
        }
    }
    float a2s = 0.f;
    b = pe_off[w]; e = pe_off[w+1];
    int deg = e-b;
    for (int cb=b; cb<e; cb+=64){
        int j = cb+lane;
        int s = (j<e)? pe_csr[j] : 0;
        int lim = min(64, e-cb);
        int q = 0;
        for (; q+4<=lim; q+=4){
            int s0=__shfl(s,q,64),   s1=__shfl(s,q+1,64);
            int s2=__shfl(s,q+2,64), s3=__shfl(s,q+3,64);
            float v0 = b2f((uint32_t)p2pe[(size_t)s0*64 + lane]);
            float v1 = b2f((uint32_t)p2pe[(size_t)s1*64 + lane]);
            float v2 = b2f((uint32_t)p2pe[(size_t)s2*64 + lane]);
            float v3 = b2f((uint32_t)p2pe[(size_t)s3*64 + lane]);
            a2s += v0 + v1 + v2 + v3;
        }
        for (; q<lim; q++){
            int sq = __shfl(s,q,64);
            a2s += b2f((uint32_t)p2pe[(size_t)sq*64 + lane]);
        }
    }
    float s2f = 1.f/fmaxf((float)deg,1.f);
    out[(size_t)w*64 + lane] += acc + a2s*s2f;
}

// GEMV helpers (bf16 X)
__global__ void rowdot64b(const uint16_t* __restrict__ X, const float* __restrict__ w,
                          float* __restrict__ out, int N){
    int wid  = (blockIdx.x*blockDim.x + threadIdx.x) >> 6;
    int lane = threadIdx.x & 63;
    if (wid >= N) return;
    float v = b2f((uint32_t)X[(size_t)wid*64 + lane])*w[lane];
    for (int o=32;o;o>>=1) v += __shfl_xor(v,o,64);
    if (lane==0) out[wid]=v;
}
__global__ void rowdot128b(const uint16_t* __restrict__ X, const float* __restrict__ w,
                           float* __restrict__ out, int N){
    int wid  = (blockIdx.x*blockDim.x + threadIdx.x) >> 6;
    int lane = threadIdx.x & 63;
    if (wid >= N) return;
    float v = b2f((uint32_t)X[(size_t)wid*128 + lane])*w[lane]
            + b2f((uint32_t)X[(size_t)wid*128 + 64 + lane])*w[64+lane];
    for (int o=32;o;o>>=1) v += __shfl_xor(v,o,64);
    if (lane==0) out[wid]=v;
}

// ================= prep (unchanged) =================
constexpr int WB_WSUM   = 0;
constexpr int WB_EEWL   = 16384;
constexpr int WB_EPWL   = 32768;
constexpr int WB_PEWL   = 49152;
constexpr int WB_EPWR1  = 65536;
constexpr int WB_LINE   = 81920;
constexpr int WB_LINP   = 90112;
constexpr int WB_GATW   = 94208;
constexpr int WB_S2EPWL = 102400;
constexpr int WB_S2PEWR = 110592;
constexpr int WB_S2PEWL = 118784;
constexpr int WB_S2EPWR = 126976;

__global__ void prep(const float* Wr_ee, const float* Wr_pe,
                     const float* ee_Wl, const float* ep_Wl, const float* pe_Wl, const float* ep_Wr,
                     const float* line_w, const float* linp_w,
                     const float* gatW, const float* s2epWl, const float* s2peWr,
                     const float* s2peWl, const float* s2epWr,
                     const float* bl_ee, const float* bl_pe,
                     const float* s2_pe_bl, const float* gat_b,
                     const float* Wdst, const float* adst,
                     uint16_t* wb, float* bsum1, float* b2sum, float* vvec)
{
    int j = blockIdx.x, t = threadIdx.x;
    if (j == 12){
        if (t < HD){
            bsum1[t] = bl_ee[t] + bl_pe[t];
            float s = 0.f;
            for (int c=0;c<OUTD;c++) s += Wdst[t*OUTD + c]*adst[c];
            vvec[t] = s;
        }
        if (t < OUTD) b2sum[t] = s2_pe_bl[t] + gat_b[t];
        return;
    }
    if (j == 0){
        for (int i=t; i<16384; i+=256) wb[WB_WSUM + i] = f2b(Wr_ee[i] + Wr_pe[i]);
        return;
    }
    const float* src; uint16_t* dst; int n;
    switch(j){
        case 1:  src=ee_Wl;  dst=wb+WB_EEWL;   n=16384; break;
        case 2:  src=ep_Wl;  dst=wb+WB_EPWL;   n=16384; break;
        case 3:  src=pe_Wl;  dst=wb+WB_PEWL;   n=16384; break;
        case 4:  src=ep_Wr;  dst=wb+WB_EPWR1;  n=16384; break;
        case 5:  src=line_w; dst=wb+WB_LINE;   n=8192;  break;
        case 6:  src=linp_w; dst=wb+WB_LINP;   n=4096;  break;
        case 7:  src=gatW;   dst=wb+WB_GATW;   n=8192;  break;
        case 8:  src=s2epWl; dst=wb+WB_S2EPWL; n=8192;  break;
        case 9:  src=s2peWr; dst=wb+WB_S2PEWR; n=8192;  break;
        case 10: src=s2peWl; dst=wb+WB_S2PEWL; n=8192;  break;
        default: src=s2epWr; dst=wb+WB_S2EPWR; n=8192;  break;
    }
    for (int i=t; i<n; i+=256) dst[i] = f2b(src[i]);
}

__global__ void convx(const float* __restrict__ xe, const float* __restrict__ xp,
                      uint16_t* __restrict__ be, uint16_t* __restrict__ bp){
    const int NE4 = NE_N*64/4, NP4 = NPER_N*32/4;
    int i = blockIdx.x*blockDim.x + threadIdx.x;
    if (i < NE4){
        float4 v = ld4(xe + (size_t)i*4);
        uint2 o;
        o.x = (uint32_t)f2b(v.x) | ((uint32_t)f2b(v.y) << 16);
        o.y = (uint32_t)f2b(v.z) | ((uint32_t)f2b(v.w) << 16);
        *reinterpret_cast<uint2*>(&be[(size_t)i*4]) = o;
    } else if (i < NE4 + NP4){
        int k = i - NE4;
        float4 v = ld4(xp + (size_t)k*4);
        uint2 o;
        o.x = (uint32_t)f2b(v.x) | ((uint32_t)f2b(v.y) << 16);
        o.y = (uint32_t)f2b(v.z) | ((uint32_t)f2b(v.w) << 16);
        *reinterpret_cast<uint2*>(&bp[(size_t)k*4]) = o;
    }
}

// ---------------- workspace layout (unchanged) ----------------
constexpr size_t OFF_R0 = 0;
constexpr size_t OFF_R1 = 3200000;
constexpr size_t OFF_R2 = 4800000;
constexpr size_t OFF_R3 = 11200000;
constexpr size_t OFF_R4 = 14400000;
constexpr size_t OFF_R5 = 27200000;
constexpr size_t OFF_R6 = 33600000;
constexpr size_t OFF_R7 = 40000000;
constexpr size_t OFF_R8 = 43200000;
constexpr size_t OFF_AS = 49600000;
constexpr size_t OFF_AD = 49700000;
constexpr size_t OFF_WB = 49800000;
constexpr size_t OFF_BS1= 49900000;
constexpr size_t OFF_BS2= 49900128;
constexpr size_t OFF_VV = 49900192;
constexpr size_t OFF_EE_CNT = 50000000;
constexpr size_t OFF_EE_OFF = 50100000;
constexpr size_t OFF_PE_CNT = 50200008;
constexpr size_t OFF_PE_OFF = 50300008;
constexpr size_t OFF_EP_CNT = 50400016;
constexpr size_t OFF_EP_OFF = 50450016;
constexpr size_t OFF_PART   = 50500024;
constexpr size_t OFF_EE_CSR = 50500288;
constexpr size_t OFF_PE_CSR = 52100288;
constexpr size_t OFF_EP_CSR = 52900288;

extern "C" void kernel_launch(void* const* d_in, const int* in_sizes, int n_in,
                              void* d_out, int out_size, void* d_ws, size_t ws_size,
                              hipStream_t stream)
{
    const float* x_emp = (const float*)d_in[0];
    const float* x_per = (const float*)d_in[1];
    const int* ee_src = (const int*)d_in[2];
    const int* ee_dst = (const int*)d_in[3];
    const int* pe_src = (const int*)d_in[4];
    const int* pe_dst = (const int*)d_in[5];
    const int* ep_src = (const int*)d_in[6];
    const int* ep_dst = (const int*)d_in[7];
    const float* lin_emp_w=(const float*)d_in[8],  *lin_emp_b=(const float*)d_in[9];
    const float* lin_per_w=(const float*)d_in[10], *lin_per_b=(const float*)d_in[11];
    const float* s1_ee_Wl=(const float*)d_in[12], *s1_ee_bl=(const float*)d_in[13], *s1_ee_Wr=(const float*)d_in[14];
    const float* s1_pe_Wl=(const float*)d_in[15], *s1_pe_bl=(const float*)d_in[16], *s1_pe_Wr=(const float*)d_in[17];
    const float* s1_ep_Wl=(const float*)d_in[18], *s1_ep_bl=(const float*)d_in[19], *s1_ep_Wr=(const float*)d_in[20];
    const float* gat_Wsrc=(const float*)d_in[21], *gat_Wdst=(const float*)d_in[22];
    const float* gat_asrc=(const float*)d_in[23], *gat_adst=(const float*)d_in[24], *gat_b=(const float*)d_in[25];
    const float* s2_pe_Wl=(const float*)d_in[26], *s2_pe_bl=(const float*)d_in[27], *s2_pe_Wr=(const float*)d_in[28];
    const float* s2_ep_Wl=(const float*)d_in[29], *s2_ep_bl=(const float*)d_in[30], *s2_ep_Wr=(const float*)d_in[31];

    float* ws = (float*)d_ws;
    int*   wi = (int*)d_ws;
    float* out_emp = (float*)d_out;
    float* out_per = out_emp + (size_t)NE_N*OUTD;

    uint16_t* xbe     = (uint16_t*)(ws + OFF_R0);
    uint16_t* zsB     = (uint16_t*)(ws + OFF_R0);
    uint16_t* xbp     = (uint16_t*)(ws + OFF_R1);
    uint16_t* p2peB   = (uint16_t*)(ws + OFF_R1);
    uint16_t* h_empB  = (uint16_t*)(ws + OFF_R2);
    uint16_t* emp1B   = (uint16_t*)(ws + OFF_R2);
    uint16_t* h_perB  = (uint16_t*)(ws + OFF_R3);
    uint16_t* per1B   = (uint16_t*)(ws + OFF_R3);
    float*    emp1F   = ws + OFF_R4;
    uint16_t* p2epB   = (uint16_t*)(ws + OFF_R4);
    float*    per1F   = ws + OFF_R5;
    uint16_t* proj_eeB= (uint16_t*)(ws + OFF_R6);
    uint16_t* proj_peB= (uint16_t*)(ws + OFF_R7);
    uint16_t* proj_epB= (uint16_t*)(ws + OFF_R8);
    float* a_s   = ws + OFF_AS;
    float* a_d   = ws + OFF_AD;
    uint16_t* WB = (uint16_t*)(ws + OFF_WB);
    float* bsum1 = ws + OFF_BS1;
    float* b2sum = ws + OFF_BS2;
    float* vvec  = ws + OFF_VV;

    int* ee_cnt = wi + OFF_EE_CNT; int* ee_off = wi + OFF_EE_OFF; int* ee_csr = wi + OFF_EE_CSR;
    int* pe_cnt = wi + OFF_PE_CNT; int* pe_off = wi + OFF_PE_OFF; int* pe_csr = wi + OFF_PE_CSR;
    int* ep_cnt = wi + OFF_EP_CNT; int* ep_off = wi + OFF_EP_OFF; int* ep_csr = wi + OFF_EP_CSR;
    int* part   = wi + OFF_PART;

    const int GE = ceil_div(NE_N,256), GP = ceil_div(NPER_N,256);

    hipMemsetAsync(ee_cnt, 0, 100000*sizeof(int), stream);
    hipMemsetAsync(pe_cnt, 0, 100000*sizeof(int), stream);
    hipMemsetAsync(ep_cnt, 0,  50000*sizeof(int), stream);

    prep<<<13,256,0,stream>>>(s1_ee_Wr, s1_pe_Wr, s1_ee_Wl, s1_ep_Wl, s1_pe_Wl, s1_ep_Wr,
                              lin_emp_w, lin_per_w,
                              gat_Wsrc, s2_ep_Wl, s2_pe_Wr, s2_pe_Wl, s2_ep_Wr,
                              s1_ee_bl, s1_pe_bl, s2_pe_bl, gat_b, gat_Wdst, gat_adst,
                              WB, bsum1, b2sum, vvec);
    convx<<<ceil_div(NE_N*64/4 + NPER_N*32/4, 256),256,0,stream>>>(x_emp, x_per, xbe, xbp);

    count_int<<<ceil_div(NEE,256),256,0,stream>>>(ee_dst, ee_cnt, NEE);
    count_int<<<ceil_div(NPE,256),256,0,stream>>>(pe_dst, pe_cnt, NPE);
    count_int<<<ceil_div(NEP,256),256,0,stream>>>(ep_dst, ep_cnt, NEP);
    {   int nb = ceil_div(NE_N,1024);
        scan_block<<<nb,256,0,stream>>>(ee_cnt, ee_off, part, NE_N);
        scan_partial<<<1,64,0,stream>>>(part, nb);
        add_base<<<ceil_div(NE_N+1,256),256,0,stream>>>(ee_off, part, NE_N, NEE);
        fill_csr<<<ceil_div(NEE,256),256,0,stream>>>(ee_src, ee_dst, ee_off, ee_cnt, ee_csr, NEE);
    }
    {   int nb = ceil_div(NE_N,1024);
        scan_block<<<nb,256,0,stream>>>(pe_cnt, pe_off, part, NE_N);
        scan_partial<<<1,64,0,stream>>>(part, nb);
        add_base<<<ceil_div(NE_N+1,256),256,0,stream>>>(pe_off, part, NE_N, NPE);
        fill_csr<<<ceil_div(NPE,256),256,0,stream>>>(pe_src, pe_dst, pe_off, pe_cnt, pe_csr, NPE);
    }
    {   int nb = ceil_div(NPER_N,1024);
        scan_block<<<nb,256,0,stream>>>(ep_cnt, ep_off, part, NPER_N);
        scan_partial<<<1,64,0,stream>>>(part, nb);
        add_base<<<ceil_div(NPER_N+1,256),256,0,stream>>>(ep_off, part, NPER_N, NEP);
        fill_csr<<<ceil_div(NEP,256),256,0,stream>>>(ep_src, ep_dst, ep_off, ep_cnt, ep_csr, NEP);
    }

    {
        Segs g{};
        g.s[0] = Seg{WB+WB_LINE,    lin_emp_b,    (void*)h_empB,      128,128,2};
        g.s[1] = Seg{WB+WB_LINE+64, lin_emp_b+64, (void*)(h_empB+64), 128,128,2};
        g.s[2]=g.s[0]; g.s[3]=g.s[0]; g.s[4]=g.s[0]; g.s[5]=g.s[0];
        gemm_mfma<64><<<dim3(GE,2),256,0,stream>>>(xbe, NE_N, g);
    }
    {
        Segs g{};
        g.s[0] = Seg{WB+WB_LINP,    lin_per_b,    (void*)h_perB,      128,128,2};
        g.s[1] = Seg{WB+WB_LINP+64, lin_per_b+64, (void*)(h_perB+64), 128,128,2};
        g.s[2]=g.s[0]; g.s[3]=g.s[0]; g.s[4]=g.s[0]; g.s[5]=g.s[0];
        gemm_mfma<32><<<dim3(GP,2),256,0,stream>>>(xbp, NPER_N, g);
    }

    {
        Segs g{};
        g.s[0] = Seg{WB+WB_WSUM,    bsum1,    (void*)emp1F,        128,128,0};
        g.s[1] = Seg{WB+WB_WSUM+64, bsum1+64, (void*)(emp1F+64),   128,128,0};
        g.s[2] = Seg{WB+WB_EEWL,    nullptr,  (void*)proj_eeB,     128,128,1};
        g.s[3] = Seg{WB+WB_EEWL+64, nullptr,  (void*)(proj_eeB+64),128,128,1};
        g.s[4] = Seg{WB+WB_EPWL,    nullptr,  (void*)proj_epB,     128,128,1};
        g.s[5] = Seg{WB+WB_EPWL+64, nullptr,  (void*)(proj_epB+64),128,128,1};
        gemm_mfma<128><<<dim3(GE,6),256,0,stream>>>(h_empB, NE_N, g);
    }
    {
        Segs g{};
        g.s[0] = Seg{WB+WB_PEWL,    nullptr,     (void*)proj_peB,     128,128,1};
        g.s[1] = Seg{WB+WB_PEWL+64, nullptr,     (void*)(proj_peB+64),128,128,1};
        g.s[2] = Seg{WB+WB_EPWR1,   s1_ep_bl,    (void*)per1F,        128,128,0};
        g.s[3] = Seg{WB+WB_EPWR1+64,s1_ep_bl+64, (void*)(per1F+64),   128,128,0};
        g.s[4]=g.s[0]; g.s[5]=g.s[0];
        gemm_mfma<128><<<dim3(GP,4),256,0,stream>>>(h_perB, NPER_N, g);
    }
    agg_emp1<<<ceil_div((long long)NE_N*64,256),256,0,stream>>>(proj_eeB, proj_peB, ee_off, ee_csr, pe_off, pe_csr, emp1F, emp1B);
    agg_per1<<<ceil_div((long long)NPER_N*64,256),256,0,stream>>>(proj_epB, ep_off, ep_csr, per1F, per1B);

    {
        Segs g{};
        g.s[0] = Seg{WB+WB_GATW,   nullptr, (void*)zsB,     64,64,1};
        g.s[1] = Seg{WB+WB_S2EPWL, nullptr, (void*)p2epB,   64,64,1};
        g.s[2] = Seg{WB+WB_S2PEWR, b2sum,   (void*)out_emp, 64,64,0};
        g.s[3]=g.s[0]; g.s[4]=g.s[0]; g.s[5]=g.s[0];
        gemm_mfma<128><<<dim3(GE,3),256,0,stream>>>(emp1B, NE_N, g);
    }
    rowdot64b <<<ceil_div(NE_N,4),256,0,stream>>>(zsB,   gat_asrc, a_s, NE_N);
    rowdot128b<<<ceil_div(NE_N,4),256,0,stream>>>(emp1B, vvec,     a_d, NE_N);
    {
        Segs g{};
        g.s[0] = Seg{WB+WB_S2PEWL, nullptr,  (void*)p2peB,   64,64,1};
        g.s[1] = Seg{WB+WB_S2EPWR, s2_ep_bl, (void*)out_per, 64,64,0};
        g.s[2]=g.s[0]; g.s[3]=g.s[0]; g.s[4]=g.s[0]; g.s[5]=g.s[0];
        gemm_mfma<128><<<dim3(GP,2),256,0,stream>>>(per1B, NPER_N, g);
    }

    gat_sage_emp2<<<ceil_div((long long)NE_N*64,256),256,0,stream>>>(ee_off, ee_csr, pe_off, pe_csr, a_s, a_d, zsB, p2peB, out_emp);
    agg_per2<<<ceil_div((long long)NPER_N*64,256),256,0,stream>>>(p2epB, ep_off, ep_csr, out_per);
}

// Round 8
// 809.309 us; speedup vs baseline: 20.3522x; 1.0775x over previous
//
#include <hip/hip_runtime.h>
#include <cstdint>

#define NE_N   100000
#define NPER_N 50000
#define HD     128
#define OUTD   64
#define NEE    1600000
#define NPE    800000
#define NEP    800000

static inline int ceil_div(long long a, long long b){ return (int)((a + b - 1)/b); }

__device__ __forceinline__ float4 ld4(const float* p){ return *reinterpret_cast<const float4*>(p); }
__device__ __forceinline__ void st4(float* p, float4 v){ *reinterpret_cast<float4*>(p) = v; }
__device__ __forceinline__ uint16_t f2b(float f){            // fp32 -> bf16 RNE
    uint32_t u = __float_as_uint(f);
    u += 0x7fffu + ((u >> 16) & 1u);
    return (uint16_t)(u >> 16);
}
__device__ __forceinline__ float b2f(uint32_t u){ return __uint_as_float(u << 16); }

typedef short v8s __attribute__((ext_vector_type(8)));
typedef float v4f __attribute__((ext_vector_type(4)));

// ================= MFMA bf16 GEMM (unchanged, proven) =================
struct Seg { const uint16_t* W; const float* b; void* C; int ldw; int ldc; int mode; };
struct Segs { Seg s[6]; };

template<int K>
__global__ __launch_bounds__(256)
void gemm_mfma(const uint16_t* __restrict__ A, int N, Segs segs)
{
    constexpr int NKS  = K / 32;
    constexpr int PADK = K + 8;
    __shared__ __align__(16) uint16_t Wt[64 * PADK];

    Seg sg = segs.s[blockIdx.y];

    const int t = threadIdx.x;
    for (int i = t; i < K*64; i += 256){
        int k = i >> 6, c = i & 63;
        Wt[c*PADK + k] = sg.W[(size_t)k*sg.ldw + c];
    }
    __syncthreads();

    const int lane = t & 63, wid = t >> 6;
    const int l16 = lane & 15, lg = lane >> 4;
    const int rowbase = blockIdx.x*256 + wid*64;

    v4f acc[4][4];
#pragma unroll
    for (int i=0;i<4;i++)
#pragma unroll
        for (int j=0;j<4;j++) acc[i][j] = (v4f){0.f,0.f,0.f,0.f};

#pragma unroll
    for (int ks=0; ks<NKS; ks++){
        const int koff = ks*32 + lg*8;
        v8s a[4], b[4];
#pragma unroll
        for (int rt=0;rt<4;rt++){
            int r = rowbase + rt*16 + l16; if (r > N-1) r = N-1;
            a[rt] = *reinterpret_cast<const v8s*>(&A[(size_t)r*K + koff]);
        }
#pragma unroll
        for (int ct=0;ct<4;ct++)
            b[ct] = *reinterpret_cast<const v8s*>(&Wt[(ct*16 + l16)*PADK + koff]);
#pragma unroll
        for (int rt=0;rt<4;rt++)
#pragma unroll
            for (int ct=0;ct<4;ct++)
                acc[rt][ct] = __builtin_amdgcn_mfma_f32_16x16x32_bf16(a[rt], b[ct], acc[rt][ct], 0, 0, 0);
    }

    const int mode = sg.mode, ldc = sg.ldc;
    float bias[4];
    if (mode != 1){
#pragma unroll
        for (int ct=0;ct<4;ct++) bias[ct] = sg.b[ct*16 + l16];
    }
#pragma unroll
    for (int rt=0;rt<4;rt++){
#pragma unroll
        for (int rg=0;rg<4;rg++){
            int r = rowbase + rt*16 + lg*4 + rg;
            if (r < N){
#pragma unroll
                for (int ct=0;ct<4;ct++){
                    float v = acc[rt][ct][rg];
                    int c = ct*16 + l16;
                    if (mode == 0)
                        ((float*)sg.C)[(size_t)r*ldc + c] = v + bias[ct];
                    else if (mode == 1)
                        ((uint16_t*)sg.C)[(size_t)r*ldc + c] = f2b(v);
                    else
                        ((uint16_t*)sg.C)[(size_t)r*ldc + c] = f2b(fmaxf(v + bias[ct], 0.f));
                }
            }
        }
    }
}

// ================= CSR build (consolidated) =================
// cnt_all: [ee 100000 | pe 100000 | ep 50000] contiguous
__global__ void count_all(const int* __restrict__ ee, const int* __restrict__ pe,
                          const int* __restrict__ ep, int* __restrict__ cnt){
    int i = blockIdx.x*blockDim.x + threadIdx.x;
    if (i < NEE) atomicAdd(&cnt[ee[i]], 1);
    else if (i < NEE+NPE) atomicAdd(&cnt[100000 + pe[i-NEE]], 1);
    else if (i < NEE+NPE+NEP) atomicAdd(&cnt[200000 + ep[i-NEE-NPE]], 1);
}
__global__ __launch_bounds__(256)
void scan_block3(const int* __restrict__ cnt_all, int* __restrict__ ee_off,
                 int* __restrict__ pe_off, int* __restrict__ ep_off,
                 int* __restrict__ partial){
    int r = blockIdx.y;
    const int* cnt = cnt_all + (r==0 ? 0 : (r==1 ? 100000 : 200000));
    int* off = (r==0) ? ee_off : (r==1 ? pe_off : ep_off);
    int n = (r==2) ? NPER_N : NE_N;
    int* part = partial + r*128;

    __shared__ int sh[256];
    int t = threadIdx.x;
    int base = blockIdx.x*1024 + t*4;
    int v0 = (base  <n)?cnt[base  ]:0;
    int v1 = (base+1<n)?cnt[base+1]:0;
    int v2 = (base+2<n)?cnt[base+2]:0;
    int v3 = (base+3<n)?cnt[base+3]:0;
    int tsum = v0+v1+v2+v3;
    sh[t]=tsum; __syncthreads();
    for (int d=1; d<256; d<<=1){
        int x = (t>=d)? sh[t-d] : 0;
        __syncthreads();
        sh[t] += x;
        __syncthreads();
    }
    int ex = sh[t]-tsum;
    if (base  <n) off[base  ]=ex;
    if (base+1<n) off[base+1]=ex+v0;
    if (base+2<n) off[base+2]=ex+v0+v1;
    if (base+3<n) off[base+3]=ex+v0+v1+v2;
    if (t==255) part[blockIdx.x]=sh[255];
}
__global__ void scan_partial3(int* __restrict__ partial){
    int r = blockIdx.x;
    if (threadIdx.x != 0) return;
    int n = (r==2) ? NPER_N : NE_N;
    int nb = (n + 1023) >> 10;
    int* p = partial + r*128;
    int run = 0;
    for (int i=0;i<nb;i++){ int v=p[i]; p[i]=run; run+=v; }
}
__global__ void add_base3(int* __restrict__ ee_off, int* __restrict__ pe_off,
                          int* __restrict__ ep_off, const int* __restrict__ partial){
    int i = blockIdx.x*blockDim.x + threadIdx.x;
    if (i <= NE_N){
        if (i < NE_N) ee_off[i] += partial[i>>10];
        else ee_off[NE_N] = NEE;
    } else if (i <= 2*NE_N + 1){
        int k = i - (NE_N+1);
        if (k < NE_N) pe_off[k] += partial[128 + (k>>10)];
        else pe_off[NE_N] = NPE;
    } else {
        int k = i - 2*(NE_N+1);
        if (k < NPER_N) ep_off[k] += partial[256 + (k>>10)];
        else if (k == NPER_N) ep_off[NPER_N] = NEP;
    }
}
__global__ void fill_all(const int* __restrict__ ee_src, const int* __restrict__ ee_dst,
                         const int* __restrict__ pe_src, const int* __restrict__ pe_dst,
                         const int* __restrict__ ep_src, const int* __restrict__ ep_dst,
                         const int* __restrict__ ee_off, const int* __restrict__ pe_off,
                         const int* __restrict__ ep_off, int* __restrict__ cnt_all,
                         int* __restrict__ ee_csr, int* __restrict__ pe_csr,
                         int* __restrict__ ep_csr){
    int i = blockIdx.x*blockDim.x + threadIdx.x;
    if (i < NEE){
        int d = ee_dst[i];
        int old = atomicAdd(&cnt_all[d], -1);
        ee_csr[ee_off[d] + old - 1] = ee_src[i];
    } else if (i < NEE+NPE){
        int k = i - NEE;
        int d = pe_dst[k];
        int old = atomicAdd(&cnt_all[100000 + d], -1);
        pe_csr[pe_off[d] + old - 1] = pe_src[k];
    } else if (i < NEE+NPE+NEP){
        int k = i - NEE - NPE;
        int d = ep_dst[k];
        int old = atomicAdd(&cnt_all[200000 + d], -1);
        ep_csr[ep_off[d] + old - 1] = ep_src[k];
    }
}

// ================= gather aggregation: 16-lane-group row loads =================
// F=128 (bf16): lane l16 owns feats [l16*8, l16*8+8) -> one uint4 (16B) per edge-row.
__global__ __launch_bounds__(256)
void agg_emp1(const uint16_t* __restrict__ proj_ee, const uint16_t* __restrict__ proj_pe,
              const int* __restrict__ ee_off, const int* __restrict__ ee_csr,
              const int* __restrict__ pe_off, const int* __restrict__ pe_csr,
              const float* __restrict__ emp1f, uint16_t* __restrict__ emp1b){
    int w    = (blockIdx.x*blockDim.x + threadIdx.x) >> 6;
    int lane = threadIdx.x & 63;
    if (w >= NE_N) return;
    int grp = lane >> 4, l16 = lane & 15;

    float a[8] = {0,0,0,0,0,0,0,0};
    int b = ee_off[w], e = ee_off[w+1];
    int dee = e - b;
    for (int cb=b; cb<e; cb+=64){
        int j = cb + lane;
        int s = (j<e) ? ee_csr[j] : -1;
        int lim = e - cb; if (lim > 64) lim = 64;
        int iters = (lim + 3) >> 2;
        for (int k=0;k<iters;k++){
            int sg = __shfl(s, k*4 + grp, 64);
            if (sg >= 0){
                uint4 u = *reinterpret_cast<const uint4*>(&proj_ee[(size_t)sg*128 + l16*8]);
                a[0]+=b2f(u.x&0xffffu); a[1]+=b2f(u.x>>16);
                a[2]+=b2f(u.y&0xffffu); a[3]+=b2f(u.y>>16);
                a[4]+=b2f(u.z&0xffffu); a[5]+=b2f(u.z>>16);
                a[6]+=b2f(u.w&0xffffu); a[7]+=b2f(u.w>>16);
            }
        }
    }
    float c[8] = {0,0,0,0,0,0,0,0};
    b = pe_off[w]; e = pe_off[w+1];
    int dpe = e - b;
    for (int cb=b; cb<e; cb+=64){
        int j = cb + lane;
        int s = (j<e) ? pe_csr[j] : -1;
        int lim = e - cb; if (lim > 64) lim = 64;
        int iters = (lim + 3) >> 2;
        for (int k=0;k<iters;k++){
            int sg = __shfl(s, k*4 + grp, 64);
            if (sg >= 0){
                uint4 u = *reinterpret_cast<const uint4*>(&proj_pe[(size_t)sg*128 + l16*8]);
                c[0]+=b2f(u.x&0xffffu); c[1]+=b2f(u.x>>16);
                c[2]+=b2f(u.y&0xffffu); c[3]+=b2f(u.y>>16);
                c[4]+=b2f(u.z&0xffffu); c[5]+=b2f(u.z>>16);
                c[6]+=b2f(u.w&0xffffu); c[7]+=b2f(u.w>>16);
            }
        }
    }
#pragma unroll
    for (int f=0;f<8;f++){
        a[f] += __shfl_xor(a[f],16,64); a[f] += __shfl_xor(a[f],32,64);
        c[f] += __shfl_xor(c[f],16,64); c[f] += __shfl_xor(c[f],32,64);
    }
    if (grp == 0){
        float s1f = 1.f/fmaxf((float)dee,1.f);
        float s2f = 1.f/fmaxf((float)dpe,1.f);
        float4 e0 = ld4(&emp1f[(size_t)w*128 + l16*8]);
        float4 e1 = ld4(&emp1f[(size_t)w*128 + l16*8 + 4]);
        float o[8];
        o[0]=fmaxf(e0.x + a[0]*s1f + c[0]*s2f, 0.f);
        o[1]=fmaxf(e0.y + a[1]*s1f + c[1]*s2f, 0.f);
        o[2]=fmaxf(e0.z + a[2]*s1f + c[2]*s2f, 0.f);
        o[3]=fmaxf(e0.w + a[3]*s1f + c[3]*s2f, 0.f);
        o[4]=fmaxf(e1.x + a[4]*s1f + c[4]*s2f, 0.f);
        o[5]=fmaxf(e1.y + a[5]*s1f + c[5]*s2f, 0.f);
        o[6]=fmaxf(e1.z + a[6]*s1f + c[6]*s2f, 0.f);
        o[7]=fmaxf(e1.w + a[7]*s1f + c[7]*s2f, 0.f);
        uint4 pk;
        pk.x = (uint32_t)f2b(o[0]) | ((uint32_t)f2b(o[1])<<16);
        pk.y = (uint32_t)f2b(o[2]) | ((uint32_t)f2b(o[3])<<16);
        pk.z = (uint32_t)f2b(o[4]) | ((uint32_t)f2b(o[5])<<16);
        pk.w = (uint32_t)f2b(o[6]) | ((uint32_t)f2b(o[7])<<16);
        *reinterpret_cast<uint4*>(&emp1b[(size_t)w*128 + l16*8]) = pk;
    }
}
__global__ __launch_bounds__(256)
void agg_per1(const uint16_t* __restrict__ proj_ep,
              const int* __restrict__ ep_off, const int* __restrict__ ep_csr,
              const float* __restrict__ per1f, uint16_t* __restrict__ per1b){
    int w    = (blockIdx.x*blockDim.x + threadIdx.x) >> 6;
    int lane = threadIdx.x & 63;
    if (w >= NPER_N) return;
    int grp = lane >> 4, l16 = lane & 15;

    float a[8] = {0,0,0,0,0,0,0,0};
    int b = ep_off[w], e = ep_off[w+1];
    int deg = e - b;
    for (int cb=b; cb<e; cb+=64){
        int j = cb + lane;
        int s = (j<e) ? ep_csr[j] : -1;
        int lim = e - cb; if (lim > 64) lim = 64;
        int iters = (lim + 3) >> 2;
        for (int k=0;k<iters;k++){
            int sg = __shfl(s, k*4 + grp, 64);
            if (sg >= 0){
                uint4 u = *reinterpret_cast<const uint4*>(&proj_ep[(size_t)sg*128 + l16*8]);
                a[0]+=b2f(u.x&0xffffu); a[1]+=b2f(u.x>>16);
                a[2]+=b2f(u.y&0xffffu); a[3]+=b2f(u.y>>16);
                a[4]+=b2f(u.z&0xffffu); a[5]+=b2f(u.z>>16);
                a[6]+=b2f(u.w&0xffffu); a[7]+=b2f(u.w>>16);
            }
        }
    }
#pragma unroll
    for (int f=0;f<8;f++){
        a[f] += __shfl_xor(a[f],16,64); a[f] += __shfl_xor(a[f],32,64);
    }
    if (grp == 0){
        float s1f = 1.f/fmaxf((float)deg,1.f);
        float4 e0 = ld4(&per1f[(size_t)w*128 + l16*8]);
        float4 e1 = ld4(&per1f[(size_t)w*128 + l16*8 + 4]);
        float o[8];
        o[0]=fmaxf(e0.x + a[0]*s1f, 0.f); o[1]=fmaxf(e0.y + a[1]*s1f, 0.f);
        o[2]=fmaxf(e0.z + a[2]*s1f, 0.f); o[3]=fmaxf(e0.w + a[3]*s1f, 0.f);
        o[4]=fmaxf(e1.x + a[4]*s1f, 0.f); o[5]=fmaxf(e1.y + a[5]*s1f, 0.f);
        o[6]=fmaxf(e1.z + a[6]*s1f, 0.f); o[7]=fmaxf(e1.w + a[7]*s1f, 0.f);
        uint4 pk;
        pk.x = (uint32_t)f2b(o[0]) | ((uint32_t)f2b(o[1])<<16);
        pk.y = (uint32_t)f2b(o[2]) | ((uint32_t)f2b(o[3])<<16);
        pk.z = (uint32_t)f2b(o[4]) | ((uint32_t)f2b(o[5])<<16);
        pk.w = (uint32_t)f2b(o[6]) | ((uint32_t)f2b(o[7])<<16);
        *reinterpret_cast<uint4*>(&per1b[(size_t)w*128 + l16*8]) = pk;
    }
}
// F=64 mean into f32 out (+=)
__global__ __launch_bounds__(256)
void agg_per2(const uint16_t* __restrict__ p2ep,
              const int* __restrict__ ep_off, const int* __restrict__ ep_csr,
              float* __restrict__ out){
    int w    = (blockIdx.x*blockDim.x + threadIdx.x) >> 6;
    int lane = threadIdx.x & 63;
    if (w >= NPER_N) return;
    int grp = lane >> 4, l16 = lane & 15;

    float a[4] = {0,0,0,0};
    int b = ep_off[w], e = ep_off[w+1];
    int deg = e - b;
    for (int cb=b; cb<e; cb+=64){
        int j = cb + lane;
        int s = (j<e) ? ep_csr[j] : -1;
        int lim = e - cb; if (lim > 64) lim = 64;
        int iters = (lim + 3) >> 2;
        for (int k=0;k<iters;k++){
            int sg = __shfl(s, k*4 + grp, 64);
            if (sg >= 0){
                uint2 u = *reinterpret_cast<const uint2*>(&p2ep[(size_t)sg*64 + l16*4]);
                a[0]+=b2f(u.x&0xffffu); a[1]+=b2f(u.x>>16);
                a[2]+=b2f(u.y&0xffffu); a[3]+=b2f(u.y>>16);
            }
        }
    }
#pragma unroll
    for (int f=0;f<4;f++){
        a[f] += __shfl_xor(a[f],16,64); a[f] += __shfl_xor(a[f],32,64);
    }
    if (grp == 0){
        float s1f = 1.f/fmaxf((float)deg,1.f);
        float4 o4 = ld4(&out[(size_t)w*64 + l16*4]);
        o4.x += a[0]*s1f; o4.y += a[1]*s1f; o4.z += a[2]*s1f; o4.w += a[3]*s1f;
        st4(&out[(size_t)w*64 + l16*4], o4);
    }
}
// GAT ee (max scan; fused exp/den/PV scan; invden at end) + SAGE pe mean, F=64
__global__ __launch_bounds__(256)
void gat_sage_emp2(const int* __restrict__ ee_off, const int* __restrict__ ee_csr,
                   const int* __restrict__ pe_off, const int* __restrict__ pe_csr,
                   const float* __restrict__ as, const float* __restrict__ ad,
                   const uint16_t* __restrict__ zs, const uint16_t* __restrict__ p2pe,
                   float* __restrict__ out){
    int w    = (blockIdx.x*blockDim.x + threadIdx.x) >> 6;
    int lane = threadIdx.x & 63;
    if (w >= NE_N) return;
    int grp = lane >> 4, l16 = lane & 15;

    float g[4] = {0,0,0,0};
    float invden = 0.f;
    int b = ee_off[w], e = ee_off[w+1];
    if (e > b){
        float add = ad[w];
        float m = -INFINITY;
        for (int j=b+lane; j<e; j+=64){
            float ev = as[ee_csr[j]] + add;
            ev = ev > 0.f ? ev : 0.2f*ev;
            m = fmaxf(m, ev);
        }
        for (int o=32;o;o>>=1) m = fmaxf(m, __shfl_xor(m,o,64));

        float den = 0.f;
        for (int cb=b; cb<e; cb+=64){
            int j = cb + lane;
            int s = 0; float ex = 0.f;
            if (j < e){
                s = ee_csr[j];
                float ev = as[s] + add;
                ev = ev > 0.f ? ev : 0.2f*ev;
                ex = expf(ev - m);
            }
            den += ex;
            int lim = e - cb; if (lim > 64) lim = 64;
            int iters = (lim + 3) >> 2;
            for (int k=0;k<iters;k++){
                int   sg = __shfl(s,  k*4 + grp, 64);
                float ag = __shfl(ex, k*4 + grp, 64);   // 0 for padded lanes
                uint2 u = *reinterpret_cast<const uint2*>(&zs[(size_t)sg*64 + l16*4]);
                g[0] += ag*b2f(u.x&0xffffu); g[1] += ag*b2f(u.x>>16);
                g[2] += ag*b2f(u.y&0xffffu); g[3] += ag*b2f(u.y>>16);
            }
        }
        for (int o=32;o;o>>=1) den += __shfl_xor(den,o,64);
        invden = 1.f/den;
    }

    float p[4] = {0,0,0,0};
    b = pe_off[w]; e = pe_off[w+1];
    int deg = e - b;
    for (int cb=b; cb<e; cb+=64){
        int j = cb + lane;
        int s = (j<e) ? pe_csr[j] : -1;
        int lim = e - cb; if (lim > 64) lim = 64;
        int iters = (lim + 3) >> 2;
        for (int k=0;k<iters;k++){
            int sg = __shfl(s, k*4 + grp, 64);
            if (sg >= 0){
                uint2 u = *reinterpret_cast<const uint2*>(&p2pe[(size_t)sg*64 + l16*4]);
                p[0]+=b2f(u.x&0xffffu); p[1]+=b2f(u.x>>16);
                p[2]+=b2f(u.y&0xffffu); p[3]+=b2f(u.y>>16);
            }
        }
    }
#pragma unroll
    for (int f=0;f<4;f++){
        g[f] += __shfl_xor(g[f],16,64); g[f] += __shfl_xor(g[f],32,64);
        p[f] += __shfl_xor(p[f],16,64); p[f] += __shfl_xor(p[f],32,64);
    }
    if (grp == 0){
        float s2f = 1.f/fmaxf((float)deg,1.f);
        float4 o4 = ld4(&out[(size_t)w*64 + l16*4]);
        o4.x += g[0]*invden + p[0]*s2f;
        o4.y += g[1]*invden + p[1]*s2f;
        o4.z += g[2]*invden + p[2]*s2f;
        o4.w += g[3]*invden + p[3]*s2f;
        st4(&out[(size_t)w*64 + l16*4], o4);
    }
}

// combined GEMVs: wid < NE_N -> a_s = zs[wid,:64]@asrc ; else a_d = emp1[wid,:128]@vvec
__global__ void rowdots(const uint16_t* __restrict__ ZS, const uint16_t* __restrict__ E1,
                        const float* __restrict__ wa, const float* __restrict__ wv,
                        float* __restrict__ a_s, float* __restrict__ a_d){
    int wid  = (blockIdx.x*blockDim.x + threadIdx.x) >> 6;
    int lane = threadIdx.x & 63;
    if (wid < NE_N){
        float v = b2f((uint32_t)ZS[(size_t)wid*64 + lane])*wa[lane];
        for (int o=32;o;o>>=1) v += __shfl_xor(v,o,64);
        if (lane==0) a_s[wid]=v;
    } else if (wid < 2*NE_N){
        int k = wid - NE_N;
        float v = b2f((uint32_t)E1[(size_t)k*128 + lane])*wv[lane]
                + b2f((uint32_t)E1[(size_t)k*128 + 64 + lane])*wv[64+lane];
        for (int o=32;o;o>>=1) v += __shfl_xor(v,o,64);
        if (lane==0) a_d[k]=v;
    }
}

// ================= prep (unchanged) =================
constexpr int WB_WSUM   = 0;
constexpr int WB_EEWL   = 16384;
constexpr int WB_EPWL   = 32768;
constexpr int WB_PEWL   = 49152;
constexpr int WB_EPWR1  = 65536;
constexpr int WB_LINE   = 81920;
constexpr int WB_LINP   = 90112;
constexpr int WB_GATW   = 94208;
constexpr int WB_S2EPWL = 102400;
constexpr int WB_S2PEWR = 110592;
constexpr int WB_S2PEWL = 118784;
constexpr int WB_S2EPWR = 126976;

__global__ void prep(const float* Wr_ee, const float* Wr_pe,
                     const float* ee_Wl, const float* ep_Wl, const float* pe_Wl, const float* ep_Wr,
                     const float* line_w, const float* linp_w,
                     const float* gatW, const float* s2epWl, const float* s2peWr,
                     const float* s2peWl, const float* s2epWr,
                     const float* bl_ee, const float* bl_pe,
                     const float* s2_pe_bl, const float* gat_b,
                     const float* Wdst, const float* adst,
                     uint16_t* wb, float* bsum1, float* b2sum, float* vvec)
{
    int j = blockIdx.x, t = threadIdx.x;
    if (j == 12){
        if (t < HD){
            bsum1[t] = bl_ee[t] + bl_pe[t];
            float s = 0.f;
            for (int c=0;c<OUTD;c++) s += Wdst[t*OUTD + c]*adst[c];
            vvec[t] = s;
        }
        if (t < OUTD) b2sum[t] = s2_pe_bl[t] + gat_b[t];
        return;
    }
    if (j == 0){
        for (int i=t; i<16384; i+=256) wb[WB_WSUM + i] = f2b(Wr_ee[i] + Wr_pe[i]);
        return;
    }
    const float* src; uint16_t* dst; int n;
    switch(j){
        case 1:  src=ee_Wl;  dst=wb+WB_EEWL;   n=16384; break;
        case 2:  src=ep_Wl;  dst=wb+WB_EPWL;   n=16384; break;
        case 3:  src=pe_Wl;  dst=wb+WB_PEWL;   n=16384; break;
        case 4:  src=ep_Wr;  dst=wb+WB_EPWR1;  n=16384; break;
        case 5:  src=line_w; dst=wb+WB_LINE;   n=8192;  break;
        case 6:  src=linp_w; dst=wb+WB_LINP;   n=4096;  break;
        case 7:  src=gatW;   dst=wb+WB_GATW;   n=8192;  break;
        case 8:  src=s2epWl; dst=wb+WB_S2EPWL; n=8192;  break;
        case 9:  src=s2peWr; dst=wb+WB_S2PEWR; n=8192;  break;
        case 10: src=s2peWl; dst=wb+WB_S2PEWL; n=8192;  break;
        default: src=s2epWr; dst=wb+WB_S2EPWR; n=8192;  break;
    }
    for (int i=t; i<n; i+=256) dst[i] = f2b(src[i]);
}

__global__ void convx(const float* __restrict__ xe, const float* __restrict__ xp,
                      uint16_t* __restrict__ be, uint16_t* __restrict__ bp){
    const int NE4 = NE_N*64/4, NP4 = NPER_N*32/4;
    int i = blockIdx.x*blockDim.x + threadIdx.x;
    if (i < NE4){
        float4 v = ld4(xe + (size_t)i*4);
        uint2 o;
        o.x = (uint32_t)f2b(v.x) | ((uint32_t)f2b(v.y) << 16);
        o.y = (uint32_t)f2b(v.z) | ((uint32_t)f2b(v.w) << 16);
        *reinterpret_cast<uint2*>(&be[(size_t)i*4]) = o;
    } else if (i < NE4 + NP4){
        int k = i - NE4;
        float4 v = ld4(xp + (size_t)k*4);
        uint2 o;
        o.x = (uint32_t)f2b(v.x) | ((uint32_t)f2b(v.y) << 16);
        o.y = (uint32_t)f2b(v.z) | ((uint32_t)f2b(v.w) << 16);
        *reinterpret_cast<uint2*>(&bp[(size_t)k*4]) = o;
    }
}

// ---------------- workspace layout ----------------
constexpr size_t OFF_R0 = 0;
constexpr size_t OFF_R1 = 3200000;
constexpr size_t OFF_R2 = 4800000;
constexpr size_t OFF_R3 = 11200000;
constexpr size_t OFF_R4 = 14400000;
constexpr size_t OFF_R5 = 27200000;
constexpr size_t OFF_R6 = 33600000;
constexpr size_t OFF_R7 = 40000000;
constexpr size_t OFF_R8 = 43200000;
constexpr size_t OFF_AS = 49600000;
constexpr size_t OFF_AD = 49700000;
constexpr size_t OFF_WB = 49800000;
constexpr size_t OFF_BS1= 49900000;
constexpr size_t OFF_BS2= 49900128;
constexpr size_t OFF_VV = 49900192;
constexpr size_t OFF_CNT    = 50000000;   // 250000 ints (ee|pe|ep)
constexpr size_t OFF_EE_OFF = 50250000;   // 100001
constexpr size_t OFF_PE_OFF = 50350008;   // 100001
constexpr size_t OFF_EP_OFF = 50450016;   // 50001
constexpr size_t OFF_PART   = 50500024;   // 384
constexpr size_t OFF_EE_CSR = 50500416;
constexpr size_t OFF_PE_CSR = 52100416;
constexpr size_t OFF_EP_CSR = 52900416;

extern "C" void kernel_launch(void* const* d_in, const int* in_sizes, int n_in,
                              void* d_out, int out_size, void* d_ws, size_t ws_size,
                              hipStream_t stream)
{
    const float* x_emp = (const float*)d_in[0];
    const float* x_per = (const float*)d_in[1];
    const int* ee_src = (const int*)d_in[2];
    const int* ee_dst = (const int*)d_in[3];
    const int* pe_src = (const int*)d_in[4];
    const int* pe_dst = (const int*)d_in[5];
    const int* ep_src = (const int*)d_in[6];
    const int* ep_dst = (const int*)d_in[7];
    const float* lin_emp_w=(const float*)d_in[8],  *lin_emp_b=(const float*)d_in[9];
    const float* lin_per_w=(const float*)d_in[10], *lin_per_b=(const float*)d_in[11];
    const float* s1_ee_Wl=(const float*)d_in[12], *s1_ee_bl=(const float*)d_in[13], *s1_ee_Wr=(const float*)d_in[14];
    const float* s1_pe_Wl=(const float*)d_in[15], *s1_pe_bl=(const float*)d_in[16], *s1_pe_Wr=(const float*)d_in[17];
    const float* s1_ep_Wl=(const float*)d_in[18], *s1_ep_bl=(const float*)d_in[19], *s1_ep_Wr=(const float*)d_in[20];
    const float* gat_Wsrc=(const float*)d_in[21], *gat_Wdst=(const float*)d_in[22];
    const float* gat_asrc=(const float*)d_in[23], *gat_adst=(const float*)d_in[24], *gat_b=(const float*)d_in[25];
    const float* s2_pe_Wl=(const float*)d_in[26], *s2_pe_bl=(const float*)d_in[27], *s2_pe_Wr=(const float*)d_in[28];
    const float* s2_ep_Wl=(const float*)d_in[29], *s2_ep_bl=(const float*)d_in[30], *s2_ep_Wr=(const float*)d_in[31];

    float* ws = (float*)d_ws;
    int*   wi = (int*)d_ws;
    float* out_emp = (float*)d_out;
    float* out_per = out_emp + (size_t)NE_N*OUTD;

    uint16_t* xbe     = (uint16_t*)(ws + OFF_R0);
    uint16_t* zsB     = (uint16_t*)(ws + OFF_R0);
    uint16_t* xbp     = (uint16_t*)(ws + OFF_R1);
    uint16_t* p2peB   = (uint16_t*)(ws + OFF_R1);
    uint16_t* h_empB  = (uint16_t*)(ws + OFF_R2);
    uint16_t* emp1B   = (uint16_t*)(ws + OFF_R2);
    uint16_t* h_perB  = (uint16_t*)(ws + OFF_R3);
    uint16_t* per1B   = (uint16_t*)(ws + OFF_R3);
    float*    emp1F   = ws + OFF_R4;
    uint16_t* p2epB   = (uint16_t*)(ws + OFF_R4);
    float*    per1F   = ws + OFF_R5;
    uint16_t* proj_eeB= (uint16_t*)(ws + OFF_R6);
    uint16_t* proj_peB= (uint16_t*)(ws + OFF_R7);
    uint16_t* proj_epB= (uint16_t*)(ws + OFF_R8);
    float* a_s   = ws + OFF_AS;
    float* a_d   = ws + OFF_AD;
    uint16_t* WB = (uint16_t*)(ws + OFF_WB);
    float* bsum1 = ws + OFF_BS1;
    float* b2sum = ws + OFF_BS2;
    float* vvec  = ws + OFF_VV;

    int* cnt_all = wi + OFF_CNT;
    int* ee_off = wi + OFF_EE_OFF; int* ee_csr = wi + OFF_EE_CSR;
    int* pe_off = wi + OFF_PE_OFF; int* pe_csr = wi + OFF_PE_CSR;
    int* ep_off = wi + OFF_EP_OFF; int* ep_csr = wi + OFF_EP_CSR;
    int* part   = wi + OFF_PART;

    const int GE = ceil_div(NE_N,256), GP = ceil_div(NPER_N,256);

    hipMemsetAsync(cnt_all, 0, 250000*sizeof(int), stream);

    prep<<<13,256,0,stream>>>(s1_ee_Wr, s1_pe_Wr, s1_ee_Wl, s1_ep_Wl, s1_pe_Wl, s1_ep_Wr,
                              lin_emp_w, lin_per_w,
                              gat_Wsrc, s2_ep_Wl, s2_pe_Wr, s2_pe_Wl, s2_ep_Wr,
                              s1_ee_bl, s1_pe_bl, s2_pe_bl, gat_b, gat_Wdst, gat_adst,
                              WB, bsum1, b2sum, vvec);
    convx<<<ceil_div(NE_N*64/4 + NPER_N*32/4, 256),256,0,stream>>>(x_emp, x_per, xbe, xbp);

    count_all<<<ceil_div(NEE+NPE+NEP,256),256,0,stream>>>(ee_dst, pe_dst, ep_dst, cnt_all);
    scan_block3<<<dim3(ceil_div(NE_N,1024),3),256,0,stream>>>(cnt_all, ee_off, pe_off, ep_off, part);
    scan_partial3<<<3,64,0,stream>>>(part);
    add_base3<<<ceil_div(2*(NE_N+1)+NPER_N+1,256),256,0,stream>>>(ee_off, pe_off, ep_off, part);
    fill_all<<<ceil_div(NEE+NPE+NEP,256),256,0,stream>>>(ee_src, ee_dst, pe_src, pe_dst, ep_src, ep_dst,
                                                         ee_off, pe_off, ep_off, cnt_all,
                                                         ee_csr, pe_csr, ep_csr);

    {
        Segs g{};
        g.s[0] = Seg{WB+WB_LINE,    lin_emp_b,    (void*)h_empB,      128,128,2};
        g.s[1] = Seg{WB+WB_LINE+64, lin_emp_b+64, (void*)(h_empB+64), 128,128,2};
        g.s[2]=g.s[0]; g.s[3]=g.s[0]; g.s[4]=g.s[0]; g.s[5]=g.s[0];
        gemm_mfma<64><<<dim3(GE,2),256,0,stream>>>(xbe, NE_N, g);
    }
    {
        Segs g{};
        g.s[0] = Seg{WB+WB_LINP,    lin_per_b,    (void*)h_perB,      128,128,2};
        g.s[1] = Seg{WB+WB_LINP+64, lin_per_b+64, (void*)(h_perB+64), 128,128,2};
        g.s[2]=g.s[0]; g.s[3]=g.s[0]; g.s[4]=g.s[0]; g.s[5]=g.s[0];
        gemm_mfma<32><<<dim3(GP,2),256,0,stream>>>(xbp, NPER_N, g);
    }

    {
        Segs g{};
        g.s[0] = Seg{WB+WB_WSUM,    bsum1,    (void*)emp1F,        128,128,0};
        g.s[1] = Seg{WB+WB_WSUM+64, bsum1+64, (void*)(emp1F+64),   128,128,0};
        g.s[2] = Seg{WB+WB_EEWL,    nullptr,  (void*)proj_eeB,     128,128,1};
        g.s[3] = Seg{WB+WB_EEWL+64, nullptr,  (void*)(proj_eeB+64),128,128,1};
        g.s[4] = Seg{WB+WB_EPWL,    nullptr,  (void*)proj_epB,     128,128,1};
        g.s[5] = Seg{WB+WB_EPWL+64, nullptr,  (void*)(proj_epB+64),128,128,1};
        gemm_mfma<128><<<dim3(GE,6),256,0,stream>>>(h_empB, NE_N, g);
    }
    {
        Segs g{};
        g.s[0] = Seg{WB+WB_PEWL,    nullptr,     (void*)proj_peB,     128,128,1};
        g.s[1] = Seg{WB+WB_PEWL+64, nullptr,     (void*)(proj_peB+64),128,128,1};
        g.s[2] = Seg{WB+WB_EPWR1,   s1_ep_bl,    (void*)per1F,        128,128,0};
        g.s[3] = Seg{WB+WB_EPWR1+64,s1_ep_bl+64, (void*)(per1F+64),   128,128,0};
        g.s[4]=g.s[0]; g.s[5]=g.s[0];
        gemm_mfma<128><<<dim3(GP,4),256,0,stream>>>(h_perB, NPER_N, g);
    }
    agg_emp1<<<ceil_div((long long)NE_N*64,256),256,0,stream>>>(proj_eeB, proj_peB, ee_off, ee_csr, pe_off, pe_csr, emp1F, emp1B);
    agg_per1<<<ceil_div((long long)NPER_N*64,256),256,0,stream>>>(proj_epB, ep_off, ep_csr, per1F, per1B);

    {
        Segs g{};
        g.s[0] = Seg{WB+WB_GATW,   nullptr, (void*)zsB,     64,64,1};
        g.s[1] = Seg{WB+WB_S2EPWL, nullptr, (void*)p2epB,   64,64,1};
        g.s[2] = Seg{WB+WB_S2PEWR, b2sum,   (void*)out_emp, 64,64,0};
        g.s[3]=g.s[0]; g.s[4]=g.s[0]; g.s[5]=g.s[0];
        gemm_mfma<128><<<dim3(GE,3),256,0,stream>>>(emp1B, NE_N, g);
    }
    rowdots<<<ceil_div(2*NE_N,4),256,0,stream>>>(zsB, emp1B, gat_asrc, vvec, a_s, a_d);
    {
        Segs g{};
        g.s[0] = Seg{WB+WB_S2PEWL, nullptr,  (void*)p2peB,   64,64,1};
        g.s[1] = Seg{WB+WB_S2EPWR, s2_ep_bl, (void*)out_per, 64,64,0};
        g.s[2]=g.s[0]; g.s[3]=g.s[0]; g.s[4]=g.s[0]; g.s[5]=g.s[0];
        gemm_mfma<128><<<dim3(GP,2),256,0,stream>>>(per1B, NPER_N, g);
    }

    gat_sage_emp2<<<ceil_div((long long)NE_N*64,256),256,0,stream>>>(ee_off, ee_csr, pe_off, pe_csr, a_s, a_d, zsB, p2peB, out_emp);
    agg_per2<<<ceil_div((long long)NPER_N*64,256),256,0,stream>>>(p2epB, ep_off, ep_csr, out_per);
}